// Round 11
// baseline (129.064 us; speedup 1.0000x reference)
//
#include <hip/hip_runtime.h>
#include <hip/hip_bf16.h>

// B=2, T=2048, C=1024, H=16, D=64
#define TB 2048
#define CC 1024
#define HH 16
#define DD 64
#define MM 4096     // B*T
#define N3 3072     // 3*C
#define KVB 128
#define NT (TB / KVB)   // 16

typedef __bf16 bf16x8 __attribute__((ext_vector_type(8)));
typedef float f32x4 __attribute__((ext_vector_type(4)));
typedef unsigned short ushort8 __attribute__((ext_vector_type(8)));
typedef unsigned short u16;

// q pre-scale: 0.125 * log2(e)  (softmax done in exp2 domain)
#define QSCALE 0.180336880693612f

__device__ __forceinline__ u16 f2b(float f) {
    unsigned int x = __float_as_uint(f);
    x = (x + 0x7fffu + ((x >> 16) & 1u)) >> 16;
    return (u16)x;
}

__device__ __forceinline__ unsigned cvt_pk_bf16(float lo, float hi) {
    unsigned r;
    asm("v_cvt_pk_bf16_f32 %0, %1, %2" : "=v"(r) : "v"(lo), "v"(hi));
    return r;
}

__device__ __forceinline__ void gld16(const u16* g, u16* l) {
    __builtin_amdgcn_global_load_lds(
        (const __attribute__((address_space(1))) unsigned int*)g,
        (__attribute__((address_space(3))) unsigned int*)l, 16, 0, 0);
}

// ---------- merged prep: fp32->bf16 convert (x) + both weight transposes ----------
__global__ __launch_bounds__(256) void prep(const float* __restrict__ x,
                                            u16* __restrict__ xb,
                                            const float* __restrict__ wqkv,
                                            u16* __restrict__ wqkvT,
                                            const float* __restrict__ wout,
                                            u16* __restrict__ woutT) {
    __shared__ float tl[64][65];
    const int bx = blockIdx.x;
    const int tid = threadIdx.x;
    if (bx < 4096) {
        int i = (bx * 256 + tid) * 4;
        float4 v = *reinterpret_cast<const float4*>(x + i);
        union { u16 u[4]; uint2 v2; } r;
        r.u[0] = f2b(v.x); r.u[1] = f2b(v.y); r.u[2] = f2b(v.z); r.u[3] = f2b(v.w);
        *reinterpret_cast<uint2*>(xb + i) = r.v2;
        return;
    }
    const int idx = bx - 4096;              // 0..1023
    const int nb = idx & 63, kb = idx >> 6; // n-tile, k-tile
    const float* in; u16* out; int N, n0;
    if (nb < 48) { in = wqkv; out = wqkvT; N = 3072; n0 = nb * 64; }
    else         { in = wout; out = woutT; N = 1024; n0 = (nb - 48) * 64; }
    const int k0 = kb * 64;
#pragma unroll
    for (int rep = 0; rep < 16; ++rep) {
        int id2 = rep * 256 + tid;
        int r = id2 >> 6, c = id2 & 63;
        tl[r][c] = in[(size_t)(k0 + r) * N + n0 + c];
    }
    __syncthreads();
#pragma unroll
    for (int rep = 0; rep < 16; ++rep) {
        int id2 = rep * 256 + tid;
        int r = id2 >> 6, c = id2 & 63;
        out[(size_t)(n0 + r) * 1024 + k0 + c] = f2b(tl[c][r]);
    }
}

// ---------- GEMM1: 128x128 tile, BK=64, global_load_lds + XOR swizzle ----------
// V third written key-PERMUTED (matches attn PV A-fragment); Q/K thirds routed
// through LDS for coalesced 16B stores.
__global__ __launch_bounds__(256) void gemm_qkv(const u16* __restrict__ xb,   // [4096][1024]
                                                const u16* __restrict__ wT,   // [3072][1024]
                                                const float* __restrict__ bias,
                                                u16* __restrict__ qg,
                                                u16* __restrict__ kg,
                                                u16* __restrict__ vtg) {
    __shared__ u16 smem[2 * 128 * 64];           // As | Bs ; reused as [128][128] epilogue
    u16* As = smem;
    u16* Bs = smem + 128 * 64;
    const int m0 = blockIdx.y * 128, n0 = blockIdx.x * 128;
    const int tid = threadIdx.x;
    const int w = tid >> 6, lane = tid & 63, lr = lane & 15, h = lane >> 4;
    const int wr = w >> 1, wc = w & 1;
    f32x4 acc[4][4] = {};

    for (int k0 = 0; k0 < 1024; k0 += 64) {
        __syncthreads();
#pragma unroll
        for (int j = 0; j < 4; ++j) {
            int L = j * 256 + tid;
            int r = L >> 3, c = L & 7;
            int csw = (c ^ (r & 7)) << 3;
            gld16(xb + (size_t)(m0 + r) * 1024 + k0 + csw, As + L * 8);
            gld16(wT + (size_t)(n0 + r) * 1024 + k0 + csw, Bs + L * 8);
        }
        __syncthreads();
#pragma unroll
        for (int kk = 0; kk < 2; ++kk) {
            bf16x8 a[4], b[4];
            int cc = kk * 4 + h;
#pragma unroll
            for (int m = 0; m < 4; ++m) {
                int R = wr * 64 + m * 16 + lr;
                a[m] = *reinterpret_cast<const bf16x8*>((const char*)As + R * 128 + ((cc ^ (R & 7)) << 4));
            }
#pragma unroll
            for (int n = 0; n < 4; ++n) {
                int R = wc * 64 + n * 16 + lr;
                b[n] = *reinterpret_cast<const bf16x8*>((const char*)Bs + R * 128 + ((cc ^ (R & 7)) << 4));
            }
#pragma unroll
            for (int m = 0; m < 4; ++m)
#pragma unroll
                for (int n = 0; n < 4; ++n)
                    acc[m][n] = __builtin_amdgcn_mfma_f32_16x16x32_bf16(a[m], b[n], acc[m][n], 0, 0, 0);
        }
    }

    const int nthird = n0 >> 10;    // uniform per block (128 | 1024)
    const int b = m0 >> 11, t0 = m0 & 2047;
    if (nthird == 2) {
        // ---- V: transpose 128x128 subtile through LDS with key-permute ----
        __syncthreads();
#pragma unroll
        for (int n = 0; n < 4; ++n) {
            int nloc = wc * 64 + n * 16 + lr;
            unsigned xorv = (unsigned)(nloc & 15) << 4;
            float bv = bias[n0 + nloc];
#pragma unroll
            for (int m = 0; m < 4; ++m) {
                int mloc = wr * 64 + m * 16 + h * 4;
                // permuted position: o=16a+4h+r -> 8h+4a+r within 32-block
                int mp = (mloc & ~31) | (((mloc >> 2) & 3) << 3) | (((mloc >> 4) & 1) << 2);
                union { u16 u[4]; unsigned long long ll; } pk4;
#pragma unroll
                for (int reg = 0; reg < 4; ++reg)
                    pk4.u[reg] = f2b(acc[m][n][reg] + bv);
                *reinterpret_cast<unsigned long long*>(
                    (char*)smem + nloc * 256 + ((unsigned)(mp * 2) ^ xorv)) = pk4.ll;
            }
        }
        __syncthreads();
        const int c16 = tid & 15;
#pragma unroll
        for (int step = 0; step < 8; ++step) {
            int row = (tid >> 4) + step * 16;           // nloc 0..127
            ushort8 vch = *reinterpret_cast<const ushort8*>(
                (const char*)smem + row * 256 + ((unsigned)((c16 ^ (row & 15)) << 4)));
            int c1 = (n0 + row) & 1023;
            int hh = c1 >> 6, dd = c1 & 63;
            *reinterpret_cast<ushort8*>(
                vtg + ((size_t)(b * HH + hh) * DD + dd) * TB + t0 + c16 * 8) = vch;
        }
    } else {
        // ---- Q/K: LDS round-trip for coalesced 16B stores ----
        const float qs = (nthird == 0) ? QSCALE : 1.0f;
        __syncthreads();
#pragma unroll
        for (int n = 0; n < 4; ++n) {
            int nloc = wc * 64 + n * 16 + lr;
            float bv = bias[n0 + nloc];
#pragma unroll
            for (int m = 0; m < 4; ++m) {
#pragma unroll
                for (int reg = 0; reg < 4; ++reg) {
                    int mloc = wr * 64 + m * 16 + h * 4 + reg;
                    *reinterpret_cast<u16*>((char*)smem + mloc * 256 +
                        ((unsigned)(nloc * 2) ^ ((unsigned)(mloc & 15) << 4)))
                        = f2b((acc[m][n][reg] + bv) * qs);
                }
            }
        }
        __syncthreads();
        u16* dst = (nthird == 0) ? qg : kg;
        const int c16 = tid & 15;
#pragma unroll
        for (int step = 0; step < 8; ++step) {
            int row = (tid >> 4) + step * 16;           // mloc 0..127 (t index)
            ushort8 vch = *reinterpret_cast<const ushort8*>(
                (const char*)smem + row * 256 + ((unsigned)((c16 ^ (row & 15)) << 4)));
            int colbase = c16 * 8;                      // 0..120
            int c1 = (n0 + colbase) & 1023;
            int hh = c1 >> 6, dd = c1 & 63;
            *reinterpret_cast<ushort8*>(
                dst + ((size_t)(b * HH + hh) * TB + (t0 + row)) * DD + dd) = vch;
        }
    }
}

// ---------- flash attention: 8 waves, KVB=128, 1-deep software pipeline ----------
// R11: QK^T(t+1) computed in the same iteration as softmax(t)+PV(t) -> the
// MFMA stream of the next tile fills the VALU softmax window. Buffers staged
// and read are disjoint each iteration; one barrier per tile.
__global__ __launch_bounds__(512, 4) void attn(const u16* __restrict__ qg,
                                               const u16* __restrict__ kg,
                                               const u16* __restrict__ vtg,
                                               u16* __restrict__ ao) {
    __shared__ u16 Kt[2][KVB * 64];   // [key][d], 128B rows, XOR-swizzled
    __shared__ u16 Vt[2][64 * KVB];   // [d][key-permuted], 256B rows, XOR-swizzled
    const int bh = blockIdx.x;
    const int q0 = blockIdx.y * 128;
    const int tid = threadIdx.x, w = tid >> 6, lane = tid & 63;
    const int lr = lane & 15, h = lane >> 4;
    const u16* qb = qg + (size_t)bh * TB * DD;
    const u16* kb = kg + (size_t)bh * TB * DD;
    const u16* vb = vtg + (size_t)bh * DD * TB;

#define STAGE_K(buf, kt) do {                                                           \
    _Pragma("unroll")                                                                   \
    for (int j = 0; j < 2; ++j) {                                                       \
        int L = j * 512 + tid;                                                          \
        int rk = L >> 3, ck = L & 7;                                                    \
        gld16(kb + (size_t)((kt) * KVB + rk) * DD + ((ck ^ (rk & 7)) << 3),             \
              Kt[buf] + L * 8);                                                         \
    } } while (0)
#define STAGE_V(buf, kt) do {                                                           \
    _Pragma("unroll")                                                                   \
    for (int j = 0; j < 2; ++j) {                                                       \
        int L = j * 512 + tid;                                                          \
        int rv = L >> 4, cv = L & 15;                                                   \
        gld16(vb + (size_t)rv * TB + (kt) * KVB + ((cv ^ (rv & 15)) << 3),              \
              Vt[buf] + L * 8);                                                         \
    } } while (0)

// S_{t+1} = K[t+1] Q^T from Kt[KBUF]
#define QK_PHASE(S, KBUF) do {                                                          \
    __builtin_amdgcn_s_setprio(1);                                                      \
    const u16* ktc_ = Kt[KBUF];                                                         \
    _Pragma("unroll")                                                                   \
    for (int ng = 0; ng < 8; ++ng) {                                                    \
        int R = ng * 16 + lr;                                                           \
        bf16x8 ak = *reinterpret_cast<const bf16x8*>(                                   \
            (const char*)ktc_ + R * 128 + (((h) ^ (R & 7)) << 4));                      \
        S[ng] = __builtin_amdgcn_mfma_f32_16x16x32_bf16(ak, bq[0], zero4, 0, 0, 0);     \
    }                                                                                   \
    _Pragma("unroll")                                                                   \
    for (int ng = 0; ng < 8; ++ng) {                                                    \
        int R = ng * 16 + lr;                                                           \
        bf16x8 ak = *reinterpret_cast<const bf16x8*>(                                   \
            (const char*)ktc_ + R * 128 + (((4 + h) ^ (R & 7)) << 4));                  \
        S[ng] = __builtin_amdgcn_mfma_f32_16x16x32_bf16(ak, bq[1], S[ng], 0, 0, 0);     \
    }                                                                                   \
    __builtin_amdgcn_s_setprio(0);                                                      \
} while (0)

// softmax(S) + O += P V[VBUF]
#define SMPV(S, VBUF) do {                                                              \
    const u16* vtc_ = Vt[VBUF];                                                         \
    float tmx[8];                                                                       \
    _Pragma("unroll")                                                                   \
    for (int ng = 0; ng < 8; ++ng)                                                      \
        tmx[ng] = fmaxf(fmaxf(S[ng][0], S[ng][1]), fmaxf(S[ng][2], S[ng][3]));          \
    float pm = fmaxf(fmaxf(fmaxf(tmx[0], tmx[1]), fmaxf(tmx[2], tmx[3])),               \
                     fmaxf(fmaxf(tmx[4], tmx[5]), fmaxf(tmx[6], tmx[7])));              \
    pm = fmaxf(pm, __shfl_xor(pm, 16));                                                 \
    pm = fmaxf(pm, __shfl_xor(pm, 32));                                                 \
    if (!__all(pm - m_r <= 8.0f)) {                                                     \
        float mn = fmaxf(m_r, pm);                                                      \
        float fr = __builtin_amdgcn_exp2f(m_r - mn);                                    \
        m_r = mn;                                                                       \
        l_r *= fr;                                                                      \
        _Pragma("unroll")                                                               \
        for (int reg = 0; reg < 4; ++reg) {                                             \
            float fro = __shfl(fr, h * 4 + reg);                                        \
            _Pragma("unroll")                                                           \
            for (int ngd = 0; ngd < 4; ++ngd)                                           \
                o[ngd][reg] *= fro;                                                     \
        }                                                                               \
    }                                                                                   \
    float ps[8];                                                                        \
    _Pragma("unroll")                                                                   \
    for (int ng = 0; ng < 8; ++ng) {                                                    \
        S[ng][0] = __builtin_amdgcn_exp2f(S[ng][0] - m_r);                              \
        S[ng][1] = __builtin_amdgcn_exp2f(S[ng][1] - m_r);                              \
        S[ng][2] = __builtin_amdgcn_exp2f(S[ng][2] - m_r);                              \
        S[ng][3] = __builtin_amdgcn_exp2f(S[ng][3] - m_r);                              \
        ps[ng] = (S[ng][0] + S[ng][1]) + (S[ng][2] + S[ng][3]);                         \
    }                                                                                   \
    float sum = ((ps[0] + ps[1]) + (ps[2] + ps[3])) + ((ps[4] + ps[5]) + (ps[6] + ps[7])); \
    sum += __shfl_xor(sum, 16);                                                         \
    sum += __shfl_xor(sum, 32);                                                         \
    l_r += sum;                                                                         \
    __builtin_amdgcn_s_setprio(1);                                                      \
    _Pragma("unroll")                                                                   \
    for (int kk = 0; kk < 4; ++kk) {                                                    \
        union { unsigned u[4]; bf16x8 v; } ap;                                          \
        ap.u[0] = cvt_pk_bf16(S[2 * kk][0], S[2 * kk][1]);                              \
        ap.u[1] = cvt_pk_bf16(S[2 * kk][2], S[2 * kk][3]);                              \
        ap.u[2] = cvt_pk_bf16(S[2 * kk + 1][0], S[2 * kk + 1][1]);                      \
        ap.u[3] = cvt_pk_bf16(S[2 * kk + 1][2], S[2 * kk + 1][3]);                      \
        int cpos = kk * 4 + h;                                                          \
        _Pragma("unroll")                                                               \
        for (int ngd = 0; ngd < 4; ++ngd) {                                             \
            int d = ngd * 16 + lr;                                                      \
            bf16x8 bv = *reinterpret_cast<const bf16x8*>(                               \
                (const char*)vtc_ + d * 256 + ((cpos ^ (d & 15)) << 4));                \
            o[ngd] = __builtin_amdgcn_mfma_f32_16x16x32_bf16(ap.v, bv, o[ngd], 0, 0, 0);\
        }                                                                               \
    }                                                                                   \
    __builtin_amdgcn_s_setprio(0);                                                      \
} while (0)

    bf16x8 bq[2];
#pragma unroll
    for (int kk = 0; kk < 2; ++kk)
        bq[kk] = *reinterpret_cast<const bf16x8*>(qb + (size_t)(q0 + w * 16 + lr) * DD + kk * 32 + h * 8);

    f32x4 o[4] = {};          // o[ngd][reg] = O[qrow=h*4+reg][d=ngd*16+lr]
    float m_r = -1e30f;       // running max for qrow=lr (replicated across h)
    float l_r = 0.f;
    const f32x4 zero4 = {0.f, 0.f, 0.f, 0.f};
    f32x4 sA[8], sB[8];

    // prologue: K[0],V[0],K[1] staged; S_0 computed; extra barrier protects
    // Kt[0] from being restaged while any wave still reads it (R5 lesson).
    STAGE_K(0, 0);
    STAGE_V(0, 0);
    STAGE_K(1, 1);
    __syncthreads();
    QK_PHASE(sA, 0);
    __syncthreads();

#pragma unroll 1
    for (int u = 0; u < 7; ++u) {
        const int t = 2 * u;
        // even tile t: read Kt[1] (QK of t+1), Vt[0] (PV of t); stage Kt[0], Vt[1]
        STAGE_V(1, t + 1);
        STAGE_K(0, t + 2);
        QK_PHASE(sB, 1);
        SMPV(sA, 0);
        __syncthreads();
        // odd tile t+1: read Kt[0] (QK of t+2), Vt[1] (PV of t+1); stage Kt[1], Vt[0]
        STAGE_V(0, t + 2);
        STAGE_K(1, t + 3);
        QK_PHASE(sA, 0);
        SMPV(sB, 1);
        __syncthreads();
    }
    // t = 14: V[15] staged; S_15 from K[15] (staged at t=13); consume S_14 with V[14]
    STAGE_V(1, 15);
    QK_PHASE(sB, 1);
    SMPV(sA, 0);
    __syncthreads();
    // t = 15: consume S_15 with V[15]
    SMPV(sB, 1);

#undef STAGE_K
#undef STAGE_V
#undef QK_PHASE
#undef SMPV

    float linv[4];
#pragma unroll
    for (int reg = 0; reg < 4; ++reg)
        linv[reg] = 1.0f / __shfl(l_r, h * 4 + reg);

    const int b = bh >> 4, hh = bh & 15;
#pragma unroll
    for (int ngd = 0; ngd < 4; ++ngd) {
#pragma unroll
        for (int reg = 0; reg < 4; ++reg) {
            int t = q0 + w * 16 + h * 4 + reg;
            int col = hh * DD + ngd * 16 + lr;
            ao[((size_t)(b * TB + t)) * CC + col] = f2b(o[ngd][reg] * linv[reg]);
        }
    }
}

// ---------- GEMM2: out = ao @ W_out + b_out, BM=64 BN=128 (2 blocks/CU) ----------
__global__ __launch_bounds__(256) void gemm_out(const u16* __restrict__ ao,   // [4096][1024]
                                                const u16* __restrict__ wT,   // [1024][1024]
                                                const float* __restrict__ bias,
                                                float* __restrict__ out) {
    __shared__ u16 As[64 * 64];
    __shared__ u16 Bs[128 * 64];
    const int m0 = blockIdx.y * 64, n0 = blockIdx.x * 128;
    const int tid = threadIdx.x;
    const int w = tid >> 6, lane = tid & 63, lr = lane & 15, h = lane >> 4;
    f32x4 acc[4][2] = {};

    for (int k0 = 0; k0 < 1024; k0 += 64) {
        __syncthreads();
#pragma unroll
        for (int j = 0; j < 2; ++j) {
            int L = j * 256 + tid;
            int r = L >> 3, c = L & 7;
            gld16(ao + (size_t)(m0 + r) * 1024 + k0 + ((c ^ (r & 7)) << 3), As + L * 8);
        }
#pragma unroll
        for (int j = 0; j < 4; ++j) {
            int L = j * 256 + tid;
            int r = L >> 3, c = L & 7;
            gld16(wT + (size_t)(n0 + r) * 1024 + k0 + ((c ^ (r & 7)) << 3), Bs + L * 8);
        }
        __syncthreads();
#pragma unroll
        for (int kk = 0; kk < 2; ++kk) {
            bf16x8 a[4], b[2];
            int cc = kk * 4 + h;
#pragma unroll
            for (int m = 0; m < 4; ++m) {
                int R = m * 16 + lr;
                a[m] = *reinterpret_cast<const bf16x8*>((const char*)As + R * 128 + ((cc ^ (R & 7)) << 4));
            }
#pragma unroll
            for (int n = 0; n < 2; ++n) {
                int R = w * 32 + n * 16 + lr;
                b[n] = *reinterpret_cast<const bf16x8*>((const char*)Bs + R * 128 + ((cc ^ (R & 7)) << 4));
            }
#pragma unroll
            for (int m = 0; m < 4; ++m)
#pragma unroll
                for (int n = 0; n < 2; ++n)
                    acc[m][n] = __builtin_amdgcn_mfma_f32_16x16x32_bf16(a[m], b[n], acc[m][n], 0, 0, 0);
        }
    }

#pragma unroll
    for (int n = 0; n < 2; ++n) {
        int ng = n0 + w * 32 + n * 16 + lr;
        float bv = bias[ng];
#pragma unroll
        for (int m = 0; m < 4; ++m) {
#pragma unroll
            for (int reg = 0; reg < 4; ++reg) {
                int mg = m0 + m * 16 + h * 4 + reg;
                out[(size_t)mg * 1024 + ng] = acc[m][n][reg] + bv;
            }
        }
    }
}

extern "C" void kernel_launch(void* const* d_in, const int* in_sizes, int n_in,
                              void* d_out, int out_size, void* d_ws, size_t ws_size,
                              hipStream_t stream) {
    const float* x     = (const float*)d_in[0];
    const float* W_qkv = (const float*)d_in[1];
    const float* b_qkv = (const float*)d_in[2];
    const float* W_out = (const float*)d_in[3];
    const float* b_out = (const float*)d_in[4];
    float* out = (float*)d_out;

    char* ws = (char*)d_ws;
    u16* xb    = (u16*)(ws);                       // 8 MB  x bf16 [4096][1024]
    u16* wqkvT = (u16*)(ws + (size_t)( 8u << 20)); // 6 MB  W_qkv^T bf16 [3072][1024]
    u16* woutT = (u16*)(ws + (size_t)(14u << 20)); // 2 MB  W_out^T bf16 [1024][1024]
    u16* qg    = (u16*)(ws + (size_t)(16u << 20)); // 8 MB  Q [B,H,T,D] (pre-scaled)
    u16* kg    = (u16*)(ws + (size_t)(24u << 20)); // 8 MB  K [B,H,T,D]
    u16* vtg   = (u16*)(ws + (size_t)(32u << 20)); // 8 MB  V^T [B,H,D,T] key-permuted
    u16* ao    = xb;                               // reuse x buffer for attn-out

    hipLaunchKernelGGL(prep, dim3(5120), dim3(256), 0, stream, x, xb, W_qkv, wqkvT, W_out, woutT);
    hipLaunchKernelGGL(gemm_qkv, dim3(24, 32), dim3(256), 0, stream, xb, wqkvT, b_qkv, qg, kg, vtg);
    hipLaunchKernelGGL(attn, dim3(32, 16), dim3(512), 0, stream, qg, kg, vtg, ao);
    hipLaunchKernelGGL(gemm_out, dim3(8, 64), dim3(256), 0, stream, ao, woutT, b_out, out);
}

// Round 12
// 118.733 us; speedup vs baseline: 1.0870x; 1.0870x over previous
//
#include <hip/hip_runtime.h>
#include <hip/hip_bf16.h>

// B=2, T=2048, C=1024, H=16, D=64
#define TB 2048
#define CC 1024
#define HH 16
#define DD 64
#define MM 4096     // B*T
#define N3 3072     // 3*C
#define KVB 128
#define NT (TB / KVB)   // 16

typedef __bf16 bf16x8 __attribute__((ext_vector_type(8)));
typedef float f32x4 __attribute__((ext_vector_type(4)));
typedef float f32x16 __attribute__((ext_vector_type(16)));
typedef unsigned short ushort8 __attribute__((ext_vector_type(8)));
typedef unsigned short u16;

// q pre-scale: 0.125 * log2(e)  (softmax done in exp2 domain)
#define QSCALE 0.180336880693612f

__device__ __forceinline__ u16 f2b(float f) {
    unsigned int x = __float_as_uint(f);
    x = (x + 0x7fffu + ((x >> 16) & 1u)) >> 16;
    return (u16)x;
}

__device__ __forceinline__ unsigned cvt_pk_bf16(float lo, float hi) {
    unsigned r;
    asm("v_cvt_pk_bf16_f32 %0, %1, %2" : "=v"(r) : "v"(lo), "v"(hi));
    return r;
}

__device__ __forceinline__ void gld16(const u16* g, u16* l) {
    __builtin_amdgcn_global_load_lds(
        (const __attribute__((address_space(1))) unsigned int*)g,
        (__attribute__((address_space(3))) unsigned int*)l, 16, 0, 0);
}

// ---------- merged prep: fp32->bf16 convert (x) + both weight transposes ----------
__global__ __launch_bounds__(256) void prep(const float* __restrict__ x,
                                            u16* __restrict__ xb,
                                            const float* __restrict__ wqkv,
                                            u16* __restrict__ wqkvT,
                                            const float* __restrict__ wout,
                                            u16* __restrict__ woutT) {
    __shared__ float tl[64][65];
    const int bx = blockIdx.x;
    const int tid = threadIdx.x;
    if (bx < 4096) {
        int i = (bx * 256 + tid) * 4;
        float4 v = *reinterpret_cast<const float4*>(x + i);
        union { u16 u[4]; uint2 v2; } r;
        r.u[0] = f2b(v.x); r.u[1] = f2b(v.y); r.u[2] = f2b(v.z); r.u[3] = f2b(v.w);
        *reinterpret_cast<uint2*>(xb + i) = r.v2;
        return;
    }
    const int idx = bx - 4096;              // 0..1023
    const int nb = idx & 63, kb = idx >> 6; // n-tile, k-tile
    const float* in; u16* out; int N, n0;
    if (nb < 48) { in = wqkv; out = wqkvT; N = 3072; n0 = nb * 64; }
    else         { in = wout; out = woutT; N = 1024; n0 = (nb - 48) * 64; }
    const int k0 = kb * 64;
#pragma unroll
    for (int rep = 0; rep < 16; ++rep) {
        int id2 = rep * 256 + tid;
        int r = id2 >> 6, c = id2 & 63;
        tl[r][c] = in[(size_t)(k0 + r) * N + n0 + c];
    }
    __syncthreads();
#pragma unroll
    for (int rep = 0; rep < 16; ++rep) {
        int id2 = rep * 256 + tid;
        int r = id2 >> 6, c = id2 & 63;
        out[(size_t)(n0 + r) * 1024 + k0 + c] = f2b(tl[c][r]);
    }
}

// ---------- GEMM1: 128x128 tile, BK=64, global_load_lds + XOR swizzle ----------
// V third written key-PERMUTED: within each 16-token block, token k stored at
// slot swap23(k) (bits 2<->3) -- matches attn's 32x32 PV A/B fragment order.
__global__ __launch_bounds__(256) void gemm_qkv(const u16* __restrict__ xb,   // [4096][1024]
                                                const u16* __restrict__ wT,   // [3072][1024]
                                                const float* __restrict__ bias,
                                                u16* __restrict__ qg,
                                                u16* __restrict__ kg,
                                                u16* __restrict__ vtg) {
    __shared__ u16 smem[2 * 128 * 64];           // As | Bs ; reused as [128][128] epilogue
    u16* As = smem;
    u16* Bs = smem + 128 * 64;
    const int m0 = blockIdx.y * 128, n0 = blockIdx.x * 128;
    const int tid = threadIdx.x;
    const int w = tid >> 6, lane = tid & 63, lr = lane & 15, h = lane >> 4;
    const int wr = w >> 1, wc = w & 1;
    f32x4 acc[4][4] = {};

    for (int k0 = 0; k0 < 1024; k0 += 64) {
        __syncthreads();
#pragma unroll
        for (int j = 0; j < 4; ++j) {
            int L = j * 256 + tid;
            int r = L >> 3, c = L & 7;
            int csw = (c ^ (r & 7)) << 3;
            gld16(xb + (size_t)(m0 + r) * 1024 + k0 + csw, As + L * 8);
            gld16(wT + (size_t)(n0 + r) * 1024 + k0 + csw, Bs + L * 8);
        }
        __syncthreads();
#pragma unroll
        for (int kk = 0; kk < 2; ++kk) {
            bf16x8 a[4], b[4];
            int cc = kk * 4 + h;
#pragma unroll
            for (int m = 0; m < 4; ++m) {
                int R = wr * 64 + m * 16 + lr;
                a[m] = *reinterpret_cast<const bf16x8*>((const char*)As + R * 128 + ((cc ^ (R & 7)) << 4));
            }
#pragma unroll
            for (int n = 0; n < 4; ++n) {
                int R = wc * 64 + n * 16 + lr;
                b[n] = *reinterpret_cast<const bf16x8*>((const char*)Bs + R * 128 + ((cc ^ (R & 7)) << 4));
            }
#pragma unroll
            for (int m = 0; m < 4; ++m)
#pragma unroll
                for (int n = 0; n < 4; ++n)
                    acc[m][n] = __builtin_amdgcn_mfma_f32_16x16x32_bf16(a[m], b[n], acc[m][n], 0, 0, 0);
        }
    }

    const int nthird = n0 >> 10;    // uniform per block (128 | 1024)
    const int b = m0 >> 11, t0 = m0 & 2047;
    if (nthird == 2) {
        // ---- V: transpose 128x128 subtile through LDS with key-permute ----
        __syncthreads();
#pragma unroll
        for (int n = 0; n < 4; ++n) {
            int nloc = wc * 64 + n * 16 + lr;
            unsigned xorv = (unsigned)(nloc & 15) << 4;
            float bv = bias[n0 + nloc];
#pragma unroll
            for (int m = 0; m < 4; ++m) {
                int mloc = wr * 64 + m * 16 + h * 4;
                // slot = token with bits 2<->3 swapped (within 16-block)
                int mp = (mloc & ~15) | (mloc & 3) | ((mloc & 4) << 1) | ((mloc & 8) >> 1);
                union { u16 u[4]; unsigned long long ll; } pk4;
#pragma unroll
                for (int reg = 0; reg < 4; ++reg)
                    pk4.u[reg] = f2b(acc[m][n][reg] + bv);
                *reinterpret_cast<unsigned long long*>(
                    (char*)smem + nloc * 256 + ((unsigned)(mp * 2) ^ xorv)) = pk4.ll;
            }
        }
        __syncthreads();
        const int c16 = tid & 15;
#pragma unroll
        for (int step = 0; step < 8; ++step) {
            int row = (tid >> 4) + step * 16;           // nloc 0..127
            ushort8 vch = *reinterpret_cast<const ushort8*>(
                (const char*)smem + row * 256 + ((unsigned)((c16 ^ (row & 15)) << 4)));
            int c1 = (n0 + row) & 1023;
            int hh = c1 >> 6, dd = c1 & 63;
            *reinterpret_cast<ushort8*>(
                vtg + ((size_t)(b * HH + hh) * DD + dd) * TB + t0 + c16 * 8) = vch;
        }
    } else {
        // ---- Q/K: LDS round-trip for coalesced 16B stores ----
        const float qs = (nthird == 0) ? QSCALE : 1.0f;
        __syncthreads();
#pragma unroll
        for (int n = 0; n < 4; ++n) {
            int nloc = wc * 64 + n * 16 + lr;
            float bv = bias[n0 + nloc];
#pragma unroll
            for (int m = 0; m < 4; ++m) {
#pragma unroll
                for (int reg = 0; reg < 4; ++reg) {
                    int mloc = wr * 64 + m * 16 + h * 4 + reg;
                    *reinterpret_cast<u16*>((char*)smem + mloc * 256 +
                        ((unsigned)(nloc * 2) ^ ((unsigned)(mloc & 15) << 4)))
                        = f2b((acc[m][n][reg] + bv) * qs);
                }
            }
        }
        __syncthreads();
        u16* dst = (nthird == 0) ? qg : kg;
        const int c16 = tid & 15;
#pragma unroll
        for (int step = 0; step < 8; ++step) {
            int row = (tid >> 4) + step * 16;           // mloc 0..127 (t index)
            ushort8 vch = *reinterpret_cast<const ushort8*>(
                (const char*)smem + row * 256 + ((unsigned)((c16 ^ (row & 15)) << 4)));
            int colbase = c16 * 8;                      // 0..120
            int c1 = (n0 + colbase) & 1023;
            int hh = c1 >> 6, dd = c1 & 63;
            *reinterpret_cast<ushort8*>(
                dst + ((size_t)(b * HH + hh) * TB + (t0 + row)) * DD + dd) = vch;
        }
    }
}

// ---------- flash attention: 4 waves x 32 q-rows, 32x32x16 MFMA, KVB=128 ----------
// 32x32 fragments double FLOP per LDS byte (the R10 binding pipe) and make
// softmax fully lane-local: q = lane&31, keys in-register; one shfl_xor(32).
__global__ __launch_bounds__(256, 2) void attn(const u16* __restrict__ qg,
                                               const u16* __restrict__ kg,
                                               const u16* __restrict__ vtg,
                                               u16* __restrict__ ao) {
    __shared__ u16 Kt[2][KVB * 64];   // [key][d], 128B rows, XOR-swizzled
    __shared__ u16 Vt[2][64 * KVB];   // [d][key-permuted], 256B rows, XOR-swizzled
    const int bh = blockIdx.x;
    const int q0 = blockIdx.y * 128;
    const int tid = threadIdx.x, w = tid >> 6, lane = tid & 63;
    const int ln = lane & 31, H = lane >> 5;
    const u16* qb = qg + (size_t)bh * TB * DD;
    const u16* kb = kg + (size_t)bh * TB * DD;
    const u16* vb = vtg + (size_t)bh * DD * TB;

#define STAGE(buf, kp, vp) do {                                                         \
    _Pragma("unroll")                                                                   \
    for (int j = 0; j < 4; ++j) {                                                       \
        int L = j * 256 + tid;                                                          \
        int rk = L >> 3, ck = L & 7;                                                    \
        gld16((kp) + (size_t)rk * DD + ((ck ^ (rk & 7)) << 3), Kt[buf] + L * 8);        \
        int rv = L >> 4, cv = L & 15;                                                   \
        gld16((vp) + (size_t)rv * TB + ((cv ^ (rv & 15)) << 3), Vt[buf] + L * 8);       \
    } } while (0)

    bf16x8 bq[4];        // Q[q=ln][d = dc*16 + H*8 + j]
#pragma unroll
    for (int dc = 0; dc < 4; ++dc)
        bq[dc] = *reinterpret_cast<const bf16x8*>(
            qb + (size_t)(q0 + w * 32 + ln) * DD + dc * 16 + H * 8);

    f32x16 o[2] = {};     // O^T[d = ngd*32+(reg&3)+8*(reg>>2)+4H][q=ln]
    float m_r = -1e30f;
    float l_r = 0.f;
    f32x16 zero16 = {};

    auto tile_body = [&](const u16* ktc, const u16* vtc) {
        // S^T = K Q^T : s[kb4] reg r -> S[key = kb4*32+(r&3)+8*(r>>2)+4H][q=ln]
        f32x16 s[4];
        __builtin_amdgcn_s_setprio(1);
#pragma unroll
        for (int kb4 = 0; kb4 < 4; ++kb4) {
            int R = kb4 * 32 + ln;
            const char* krow = (const char*)ktc + R * 128;
#pragma unroll
            for (int dc = 0; dc < 4; ++dc) {
                bf16x8 ak = *reinterpret_cast<const bf16x8*>(
                    krow + (((dc * 2 + H) ^ (R & 7)) << 4));
                s[kb4] = __builtin_amdgcn_mfma_f32_32x32x16_bf16(
                    ak, bq[dc], dc == 0 ? zero16 : s[kb4], 0, 0, 0);
            }
        }
        __builtin_amdgcn_s_setprio(0);

        // online softmax (exp2 domain), defer-max; fully lane-local
        float pm = s[0][0];
#pragma unroll
        for (int kb4 = 0; kb4 < 4; ++kb4) {
            float t0 = fmaxf(fmaxf(s[kb4][0], s[kb4][1]), fmaxf(s[kb4][2], s[kb4][3]));
            float t1 = fmaxf(fmaxf(s[kb4][4], s[kb4][5]), fmaxf(s[kb4][6], s[kb4][7]));
            float t2 = fmaxf(fmaxf(s[kb4][8], s[kb4][9]), fmaxf(s[kb4][10], s[kb4][11]));
            float t3 = fmaxf(fmaxf(s[kb4][12], s[kb4][13]), fmaxf(s[kb4][14], s[kb4][15]));
            pm = fmaxf(pm, fmaxf(fmaxf(t0, t1), fmaxf(t2, t3)));
        }
        pm = fmaxf(pm, __shfl_xor(pm, 32));

        if (!__all(pm - m_r <= 8.0f)) {
            float mn = fmaxf(m_r, pm);
            float fr = __builtin_amdgcn_exp2f(m_r - mn);
            m_r = mn;
            l_r *= fr;
#pragma unroll
            for (int ngd = 0; ngd < 2; ++ngd)
#pragma unroll
                for (int r = 0; r < 16; ++r)
                    o[ngd][r] *= fr;
        }

        float sum = 0.f;
#pragma unroll
        for (int kb4 = 0; kb4 < 4; ++kb4) {
            float ps = 0.f;
#pragma unroll
            for (int r = 0; r < 16; ++r) {
                s[kb4][r] = __builtin_amdgcn_exp2f(s[kb4][r] - m_r);
                ps += s[kb4][r];
            }
            sum += ps;
        }
        sum += __shfl_xor(sum, 32);
        l_r += sum;

        // O^T += V^T P^T ; V keys permuted so B-frag is the lane's own regs
        __builtin_amdgcn_s_setprio(1);
#pragma unroll
        for (int kb4 = 0; kb4 < 4; ++kb4) {
#pragma unroll
            for (int b1 = 0; b1 < 2; ++b1) {
                union { unsigned u[4]; bf16x8 v; } ap;
                ap.u[0] = cvt_pk_bf16(s[kb4][8 * b1 + 0], s[kb4][8 * b1 + 1]);
                ap.u[1] = cvt_pk_bf16(s[kb4][8 * b1 + 2], s[kb4][8 * b1 + 3]);
                ap.u[2] = cvt_pk_bf16(s[kb4][8 * b1 + 4], s[kb4][8 * b1 + 5]);
                ap.u[3] = cvt_pk_bf16(s[kb4][8 * b1 + 6], s[kb4][8 * b1 + 7]);
                int c = kb4 * 2 + b1;
#pragma unroll
                for (int ngd = 0; ngd < 2; ++ngd) {
                    int d = ngd * 32 + ln;
                    bf16x8 av = *reinterpret_cast<const bf16x8*>(
                        (const char*)vtc + d * 256 + (((c * 2 + H) ^ (d & 15)) << 4));
                    o[ngd] = __builtin_amdgcn_mfma_f32_32x32x16_bf16(av, ap.v, o[ngd], 0, 0, 0);
                }
            }
        }
        __builtin_amdgcn_s_setprio(0);
    };

    STAGE(0, kb, vb);
    const u16* kp = kb + KVB * DD;
    const u16* vp = vb + KVB;
    __syncthreads();

#pragma unroll 1
    for (int kt2 = 0; kt2 < NT / 2; ++kt2) {
        STAGE(1, kp, vp);
        kp += KVB * DD; vp += KVB;
        tile_body(Kt[0], Vt[0]);
        __syncthreads();
        if (kt2 < NT / 2 - 1) {
            STAGE(0, kp, vp);
            kp += KVB * DD; vp += KVB;
        }
        tile_body(Kt[1], Vt[1]);
        __syncthreads();
    }
#undef STAGE

    const float linv = 1.0f / l_r;
    const int b = bh >> 4, hh = bh & 15;
    const int q = q0 + w * 32 + ln;
    u16* aorow = ao + (size_t)(b * TB + q) * CC + hh * 64;
#pragma unroll
    for (int ngd = 0; ngd < 2; ++ngd) {
#pragma unroll
        for (int rg = 0; rg < 4; ++rg) {
            int dbase = ngd * 32 + 8 * rg + 4 * H;
            union { u16 u[4]; unsigned long long ll; } pk;
#pragma unroll
            for (int r2 = 0; r2 < 4; ++r2)
                pk.u[r2] = f2b(o[ngd][4 * rg + r2] * linv);
            *reinterpret_cast<unsigned long long*>(aorow + dbase) = pk.ll;
        }
    }
}

// ---------- GEMM2: out = ao @ W_out + b_out, BM=64 BN=128 (2 blocks/CU) ----------
__global__ __launch_bounds__(256) void gemm_out(const u16* __restrict__ ao,   // [4096][1024]
                                                const u16* __restrict__ wT,   // [1024][1024]
                                                const float* __restrict__ bias,
                                                float* __restrict__ out) {
    __shared__ u16 As[64 * 64];
    __shared__ u16 Bs[128 * 64];
    const int m0 = blockIdx.y * 64, n0 = blockIdx.x * 128;
    const int tid = threadIdx.x;
    const int w = tid >> 6, lane = tid & 63, lr = lane & 15, h = lane >> 4;
    f32x4 acc[4][2] = {};

    for (int k0 = 0; k0 < 1024; k0 += 64) {
        __syncthreads();
#pragma unroll
        for (int j = 0; j < 2; ++j) {
            int L = j * 256 + tid;
            int r = L >> 3, c = L & 7;
            gld16(ao + (size_t)(m0 + r) * 1024 + k0 + ((c ^ (r & 7)) << 3), As + L * 8);
        }
#pragma unroll
        for (int j = 0; j < 4; ++j) {
            int L = j * 256 + tid;
            int r = L >> 3, c = L & 7;
            gld16(wT + (size_t)(n0 + r) * 1024 + k0 + ((c ^ (r & 7)) << 3), Bs + L * 8);
        }
        __syncthreads();
#pragma unroll
        for (int kk = 0; kk < 2; ++kk) {
            bf16x8 a[4], b[2];
            int cc = kk * 4 + h;
#pragma unroll
            for (int m = 0; m < 4; ++m) {
                int R = m * 16 + lr;
                a[m] = *reinterpret_cast<const bf16x8*>((const char*)As + R * 128 + ((cc ^ (R & 7)) << 4));
            }
#pragma unroll
            for (int n = 0; n < 2; ++n) {
                int R = w * 32 + n * 16 + lr;
                b[n] = *reinterpret_cast<const bf16x8*>((const char*)Bs + R * 128 + ((cc ^ (R & 7)) << 4));
            }
#pragma unroll
            for (int m = 0; m < 4; ++m)
#pragma unroll
                for (int n = 0; n < 2; ++n)
                    acc[m][n] = __builtin_amdgcn_mfma_f32_16x16x32_bf16(a[m], b[n], acc[m][n], 0, 0, 0);
        }
    }

#pragma unroll
    for (int n = 0; n < 2; ++n) {
        int ng = n0 + w * 32 + n * 16 + lr;
        float bv = bias[ng];
#pragma unroll
        for (int m = 0; m < 4; ++m) {
#pragma unroll
            for (int reg = 0; reg < 4; ++reg) {
                int mg = m0 + m * 16 + h * 4 + reg;
                out[(size_t)mg * 1024 + ng] = acc[m][n][reg] + bv;
            }
        }
    }
}

extern "C" void kernel_launch(void* const* d_in, const int* in_sizes, int n_in,
                              void* d_out, int out_size, void* d_ws, size_t ws_size,
                              hipStream_t stream) {
    const float* x     = (const float*)d_in[0];
    const float* W_qkv = (const float*)d_in[1];
    const float* b_qkv = (const float*)d_in[2];
    const float* W_out = (const float*)d_in[3];
    const float* b_out = (const float*)d_in[4];
    float* out = (float*)d_out;

    char* ws = (char*)d_ws;
    u16* xb    = (u16*)(ws);                       // 8 MB  x bf16 [4096][1024]
    u16* wqkvT = (u16*)(ws + (size_t)( 8u << 20)); // 6 MB  W_qkv^T bf16 [3072][1024]
    u16* woutT = (u16*)(ws + (size_t)(14u << 20)); // 2 MB  W_out^T bf16 [1024][1024]
    u16* qg    = (u16*)(ws + (size_t)(16u << 20)); // 8 MB  Q [B,H,T,D] (pre-scaled)
    u16* kg    = (u16*)(ws + (size_t)(24u << 20)); // 8 MB  K [B,H,T,D]
    u16* vtg   = (u16*)(ws + (size_t)(32u << 20)); // 8 MB  V^T [B,H,D,T] key-permuted
    u16* ao    = xb;                               // reuse x buffer for attn-out

    hipLaunchKernelGGL(prep, dim3(5120), dim3(256), 0, stream, x, xb, W_qkv, wqkvT, W_out, woutT);
    hipLaunchKernelGGL(gemm_qkv, dim3(24, 32), dim3(256), 0, stream, xb, wqkvT, b_qkv, qg, kg, vtg);
    hipLaunchKernelGGL(attn, dim3(32, 16), dim3(256), 0, stream, qg, kg, vtg, ao);
    hipLaunchKernelGGL(gemm_out, dim3(8, 64), dim3(256), 0, stream, ao, woutT, b_out, out);
}

// Round 13
// 117.876 us; speedup vs baseline: 1.0949x; 1.0073x over previous
//
#include <hip/hip_runtime.h>
#include <hip/hip_bf16.h>

// B=2, T=2048, C=1024, H=16, D=64
#define TB 2048
#define CC 1024
#define HH 16
#define DD 64
#define MM 4096     // B*T
#define N3 3072     // 3*C
#define KVB 128
#define NT (TB / KVB)   // 16

typedef __bf16 bf16x8 __attribute__((ext_vector_type(8)));
typedef float f32x4 __attribute__((ext_vector_type(4)));
typedef float f32x16 __attribute__((ext_vector_type(16)));
typedef unsigned short ushort8 __attribute__((ext_vector_type(8)));
typedef unsigned short u16;

// q pre-scale: 0.125 * log2(e)  (softmax done in exp2 domain)
#define QSCALE 0.180336880693612f

__device__ __forceinline__ u16 f2b(float f) {
    unsigned int x = __float_as_uint(f);
    x = (x + 0x7fffu + ((x >> 16) & 1u)) >> 16;
    return (u16)x;
}

__device__ __forceinline__ unsigned cvt_pk_bf16(float lo, float hi) {
    unsigned r;
    asm("v_cvt_pk_bf16_f32 %0, %1, %2" : "=v"(r) : "v"(lo), "v"(hi));
    return r;
}

__device__ __forceinline__ void gld16(const u16* g, u16* l) {
    __builtin_amdgcn_global_load_lds(
        (const __attribute__((address_space(1))) unsigned int*)g,
        (__attribute__((address_space(3))) unsigned int*)l, 16, 0, 0);
}

// ---------- merged prep: fp32->bf16 convert (x) + both weight transposes ----------
__global__ __launch_bounds__(256) void prep(const float* __restrict__ x,
                                            u16* __restrict__ xb,
                                            const float* __restrict__ wqkv,
                                            u16* __restrict__ wqkvT,
                                            const float* __restrict__ wout,
                                            u16* __restrict__ woutT) {
    __shared__ float tl[64][65];
    const int bx = blockIdx.x;
    const int tid = threadIdx.x;
    if (bx < 4096) {
        int i = (bx * 256 + tid) * 4;
        float4 v = *reinterpret_cast<const float4*>(x + i);
        union { u16 u[4]; uint2 v2; } r;
        r.u[0] = f2b(v.x); r.u[1] = f2b(v.y); r.u[2] = f2b(v.z); r.u[3] = f2b(v.w);
        *reinterpret_cast<uint2*>(xb + i) = r.v2;
        return;
    }
    const int idx = bx - 4096;              // 0..1023
    const int nb = idx & 63, kb = idx >> 6; // n-tile, k-tile
    const float* in; u16* out; int N, n0;
    if (nb < 48) { in = wqkv; out = wqkvT; N = 3072; n0 = nb * 64; }
    else         { in = wout; out = woutT; N = 1024; n0 = (nb - 48) * 64; }
    const int k0 = kb * 64;
#pragma unroll
    for (int rep = 0; rep < 16; ++rep) {
        int id2 = rep * 256 + tid;
        int r = id2 >> 6, c = id2 & 63;
        tl[r][c] = in[(size_t)(k0 + r) * N + n0 + c];
    }
    __syncthreads();
#pragma unroll
    for (int rep = 0; rep < 16; ++rep) {
        int id2 = rep * 256 + tid;
        int r = id2 >> 6, c = id2 & 63;
        out[(size_t)(n0 + r) * 1024 + k0 + c] = f2b(tl[c][r]);
    }
}

// ---------- GEMM1: 128x128 tile, BK=64, global_load_lds + XOR swizzle ----------
// R13: 2D-chunked XCD swizzle — each XCD owns an 8-row x 12-col rectangle of
// the 32x24 block grid (bijective, 768 % 8 == 0): A-panels shared by 2 XCDs,
// B-panels by 4, vs 8/8 with round-robin.
// V third written key-PERMUTED: within each 16-token block, token k stored at
// slot swap23(k) (bits 2<->3) -- matches attn's 32x32 PV A/B fragment order.
__global__ __launch_bounds__(256) void gemm_qkv(const u16* __restrict__ xb,   // [4096][1024]
                                                const u16* __restrict__ wT,   // [3072][1024]
                                                const float* __restrict__ bias,
                                                u16* __restrict__ qg,
                                                u16* __restrict__ kg,
                                                u16* __restrict__ vtg) {
    __shared__ u16 smem[2 * 128 * 64];           // As | Bs ; reused as [128][128] epilogue
    u16* As = smem;
    u16* Bs = smem + 128 * 64;
    const int id = blockIdx.y * 24 + blockIdx.x;
    const int xcd = id & 7, pos = id >> 3;       // 96 blocks per XCD
    const int xr = xcd >> 1, xc = xcd & 1;       // 4 row-groups x 2 col-groups
    const int pr = pos / 12, pc = pos % 12;      // 8 x 12 rectangle
    const int m0 = (xr * 8 + pr) * 128;          // 32 rows
    const int n0 = (xc * 12 + pc) * 128;         // 24 cols
    const int tid = threadIdx.x;
    const int w = tid >> 6, lane = tid & 63, lr = lane & 15, h = lane >> 4;
    const int wr = w >> 1, wc = w & 1;
    f32x4 acc[4][4] = {};

    for (int k0 = 0; k0 < 1024; k0 += 64) {
        __syncthreads();
#pragma unroll
        for (int j = 0; j < 4; ++j) {
            int L = j * 256 + tid;
            int r = L >> 3, c = L & 7;
            int csw = (c ^ (r & 7)) << 3;
            gld16(xb + (size_t)(m0 + r) * 1024 + k0 + csw, As + L * 8);
            gld16(wT + (size_t)(n0 + r) * 1024 + k0 + csw, Bs + L * 8);
        }
        __syncthreads();
#pragma unroll
        for (int kk = 0; kk < 2; ++kk) {
            bf16x8 a[4], b[4];
            int cc = kk * 4 + h;
#pragma unroll
            for (int m = 0; m < 4; ++m) {
                int R = wr * 64 + m * 16 + lr;
                a[m] = *reinterpret_cast<const bf16x8*>((const char*)As + R * 128 + ((cc ^ (R & 7)) << 4));
            }
#pragma unroll
            for (int n = 0; n < 4; ++n) {
                int R = wc * 64 + n * 16 + lr;
                b[n] = *reinterpret_cast<const bf16x8*>((const char*)Bs + R * 128 + ((cc ^ (R & 7)) << 4));
            }
#pragma unroll
            for (int m = 0; m < 4; ++m)
#pragma unroll
                for (int n = 0; n < 4; ++n)
                    acc[m][n] = __builtin_amdgcn_mfma_f32_16x16x32_bf16(a[m], b[n], acc[m][n], 0, 0, 0);
        }
    }

    const int nthird = n0 >> 10;    // uniform per block (128 | 1024)
    const int b = m0 >> 11, t0 = m0 & 2047;
    if (nthird == 2) {
        // ---- V: transpose 128x128 subtile through LDS with key-permute ----
        __syncthreads();
#pragma unroll
        for (int n = 0; n < 4; ++n) {
            int nloc = wc * 64 + n * 16 + lr;
            unsigned xorv = (unsigned)(nloc & 15) << 4;
            float bv = bias[n0 + nloc];
#pragma unroll
            for (int m = 0; m < 4; ++m) {
                int mloc = wr * 64 + m * 16 + h * 4;
                // slot = token with bits 2<->3 swapped (within 16-block)
                int mp = (mloc & ~15) | (mloc & 3) | ((mloc & 4) << 1) | ((mloc & 8) >> 1);
                union { u16 u[4]; unsigned long long ll; } pk4;
#pragma unroll
                for (int reg = 0; reg < 4; ++reg)
                    pk4.u[reg] = f2b(acc[m][n][reg] + bv);
                *reinterpret_cast<unsigned long long*>(
                    (char*)smem + nloc * 256 + ((unsigned)(mp * 2) ^ xorv)) = pk4.ll;
            }
        }
        __syncthreads();
        const int c16 = tid & 15;
#pragma unroll
        for (int step = 0; step < 8; ++step) {
            int row = (tid >> 4) + step * 16;           // nloc 0..127
            ushort8 vch = *reinterpret_cast<const ushort8*>(
                (const char*)smem + row * 256 + ((unsigned)((c16 ^ (row & 15)) << 4)));
            int c1 = (n0 + row) & 1023;
            int hh = c1 >> 6, dd = c1 & 63;
            *reinterpret_cast<ushort8*>(
                vtg + ((size_t)(b * HH + hh) * DD + dd) * TB + t0 + c16 * 8) = vch;
        }
    } else {
        // ---- Q/K: LDS round-trip for coalesced 16B stores ----
        const float qs = (nthird == 0) ? QSCALE : 1.0f;
        __syncthreads();
#pragma unroll
        for (int n = 0; n < 4; ++n) {
            int nloc = wc * 64 + n * 16 + lr;
            float bv = bias[n0 + nloc];
#pragma unroll
            for (int m = 0; m < 4; ++m) {
#pragma unroll
                for (int reg = 0; reg < 4; ++reg) {
                    int mloc = wr * 64 + m * 16 + h * 4 + reg;
                    *reinterpret_cast<u16*>((char*)smem + mloc * 256 +
                        ((unsigned)(nloc * 2) ^ ((unsigned)(mloc & 15) << 4)))
                        = f2b((acc[m][n][reg] + bv) * qs);
                }
            }
        }
        __syncthreads();
        u16* dst = (nthird == 0) ? qg : kg;
        const int c16 = tid & 15;
#pragma unroll
        for (int step = 0; step < 8; ++step) {
            int row = (tid >> 4) + step * 16;           // mloc 0..127 (t index)
            ushort8 vch = *reinterpret_cast<const ushort8*>(
                (const char*)smem + row * 256 + ((unsigned)((c16 ^ (row & 15)) << 4)));
            int colbase = c16 * 8;                      // 0..120
            int c1 = (n0 + colbase) & 1023;
            int hh = c1 >> 6, dd = c1 & 63;
            *reinterpret_cast<ushort8*>(
                dst + ((size_t)(b * HH + hh) * TB + (t0 + row)) * DD + dd) = vch;
        }
    }
}

// ---------- flash attention: 4 waves x 32 q-rows, 32x32x16 MFMA, KVB=128 ----------
// (R12-proven; equal-best 52.8 us.) 32x32 fragments double FLOP per LDS byte
// and make softmax fully lane-local: q = lane&31; one shfl_xor(32).
__global__ __launch_bounds__(256, 2) void attn(const u16* __restrict__ qg,
                                               const u16* __restrict__ kg,
                                               const u16* __restrict__ vtg,
                                               u16* __restrict__ ao) {
    __shared__ u16 Kt[2][KVB * 64];   // [key][d], 128B rows, XOR-swizzled
    __shared__ u16 Vt[2][64 * KVB];   // [d][key-permuted], 256B rows, XOR-swizzled
    const int bh = blockIdx.x;
    const int q0 = blockIdx.y * 128;
    const int tid = threadIdx.x, w = tid >> 6, lane = tid & 63;
    const int ln = lane & 31, H = lane >> 5;
    const u16* qb = qg + (size_t)bh * TB * DD;
    const u16* kb = kg + (size_t)bh * TB * DD;
    const u16* vb = vtg + (size_t)bh * DD * TB;

#define STAGE(buf, kp, vp) do {                                                         \
    _Pragma("unroll")                                                                   \
    for (int j = 0; j < 4; ++j) {                                                       \
        int L = j * 256 + tid;                                                          \
        int rk = L >> 3, ck = L & 7;                                                    \
        gld16((kp) + (size_t)rk * DD + ((ck ^ (rk & 7)) << 3), Kt[buf] + L * 8);        \
        int rv = L >> 4, cv = L & 15;                                                   \
        gld16((vp) + (size_t)rv * TB + ((cv ^ (rv & 15)) << 3), Vt[buf] + L * 8);       \
    } } while (0)

    bf16x8 bq[4];        // Q[q=ln][d = dc*16 + H*8 + j]
#pragma unroll
    for (int dc = 0; dc < 4; ++dc)
        bq[dc] = *reinterpret_cast<const bf16x8*>(
            qb + (size_t)(q0 + w * 32 + ln) * DD + dc * 16 + H * 8);

    f32x16 o[2] = {};     // O^T[d = ngd*32+(reg&3)+8*(reg>>2)+4H][q=ln]
    float m_r = -1e30f;
    float l_r = 0.f;
    f32x16 zero16 = {};

    auto tile_body = [&](const u16* ktc, const u16* vtc) {
        // S^T = K Q^T : s[kb4] reg r -> S[key = kb4*32+(r&3)+8*(r>>2)+4H][q=ln]
        f32x16 s[4];
        __builtin_amdgcn_s_setprio(1);
#pragma unroll
        for (int kb4 = 0; kb4 < 4; ++kb4) {
            int R = kb4 * 32 + ln;
            const char* krow = (const char*)ktc + R * 128;
#pragma unroll
            for (int dc = 0; dc < 4; ++dc) {
                bf16x8 ak = *reinterpret_cast<const bf16x8*>(
                    krow + (((dc * 2 + H) ^ (R & 7)) << 4));
                s[kb4] = __builtin_amdgcn_mfma_f32_32x32x16_bf16(
                    ak, bq[dc], dc == 0 ? zero16 : s[kb4], 0, 0, 0);
            }
        }
        __builtin_amdgcn_s_setprio(0);

        // online softmax (exp2 domain), defer-max; fully lane-local
        float pm = s[0][0];
#pragma unroll
        for (int kb4 = 0; kb4 < 4; ++kb4) {
            float t0 = fmaxf(fmaxf(s[kb4][0], s[kb4][1]), fmaxf(s[kb4][2], s[kb4][3]));
            float t1 = fmaxf(fmaxf(s[kb4][4], s[kb4][5]), fmaxf(s[kb4][6], s[kb4][7]));
            float t2 = fmaxf(fmaxf(s[kb4][8], s[kb4][9]), fmaxf(s[kb4][10], s[kb4][11]));
            float t3 = fmaxf(fmaxf(s[kb4][12], s[kb4][13]), fmaxf(s[kb4][14], s[kb4][15]));
            pm = fmaxf(pm, fmaxf(fmaxf(t0, t1), fmaxf(t2, t3)));
        }
        pm = fmaxf(pm, __shfl_xor(pm, 32));

        if (!__all(pm - m_r <= 8.0f)) {
            float mn = fmaxf(m_r, pm);
            float fr = __builtin_amdgcn_exp2f(m_r - mn);
            m_r = mn;
            l_r *= fr;
#pragma unroll
            for (int ngd = 0; ngd < 2; ++ngd)
#pragma unroll
                for (int r = 0; r < 16; ++r)
                    o[ngd][r] *= fr;
        }

        float sum = 0.f;
#pragma unroll
        for (int kb4 = 0; kb4 < 4; ++kb4) {
            float ps = 0.f;
#pragma unroll
            for (int r = 0; r < 16; ++r) {
                s[kb4][r] = __builtin_amdgcn_exp2f(s[kb4][r] - m_r);
                ps += s[kb4][r];
            }
            sum += ps;
        }
        sum += __shfl_xor(sum, 32);
        l_r += sum;

        // O^T += V^T P^T ; V keys permuted so B-frag is the lane's own regs
        __builtin_amdgcn_s_setprio(1);
#pragma unroll
        for (int kb4 = 0; kb4 < 4; ++kb4) {
#pragma unroll
            for (int b1 = 0; b1 < 2; ++b1) {
                union { unsigned u[4]; bf16x8 v; } ap;
                ap.u[0] = cvt_pk_bf16(s[kb4][8 * b1 + 0], s[kb4][8 * b1 + 1]);
                ap.u[1] = cvt_pk_bf16(s[kb4][8 * b1 + 2], s[kb4][8 * b1 + 3]);
                ap.u[2] = cvt_pk_bf16(s[kb4][8 * b1 + 4], s[kb4][8 * b1 + 5]);
                ap.u[3] = cvt_pk_bf16(s[kb4][8 * b1 + 6], s[kb4][8 * b1 + 7]);
                int c = kb4 * 2 + b1;
#pragma unroll
                for (int ngd = 0; ngd < 2; ++ngd) {
                    int d = ngd * 32 + ln;
                    bf16x8 av = *reinterpret_cast<const bf16x8*>(
                        (const char*)vtc + d * 256 + (((c * 2 + H) ^ (d & 15)) << 4));
                    o[ngd] = __builtin_amdgcn_mfma_f32_32x32x16_bf16(av, ap.v, o[ngd], 0, 0, 0);
                }
            }
        }
        __builtin_amdgcn_s_setprio(0);
    };

    STAGE(0, kb, vb);
    const u16* kp = kb + KVB * DD;
    const u16* vp = vb + KVB;
    __syncthreads();

#pragma unroll 1
    for (int kt2 = 0; kt2 < NT / 2; ++kt2) {
        STAGE(1, kp, vp);
        kp += KVB * DD; vp += KVB;
        tile_body(Kt[0], Vt[0]);
        __syncthreads();
        if (kt2 < NT / 2 - 1) {
            STAGE(0, kp, vp);
            kp += KVB * DD; vp += KVB;
        }
        tile_body(Kt[1], Vt[1]);
        __syncthreads();
    }
#undef STAGE

    const float linv = 1.0f / l_r;
    const int b = bh >> 4, hh = bh & 15;
    const int q = q0 + w * 32 + ln;
    u16* aorow = ao + (size_t)(b * TB + q) * CC + hh * 64;
#pragma unroll
    for (int ngd = 0; ngd < 2; ++ngd) {
#pragma unroll
        for (int rg = 0; rg < 4; ++rg) {
            int dbase = ngd * 32 + 8 * rg + 4 * H;
            union { u16 u[4]; unsigned long long ll; } pk;
#pragma unroll
            for (int r2 = 0; r2 < 4; ++r2)
                pk.u[r2] = f2b(o[ngd][4 * rg + r2] * linv);
            *reinterpret_cast<unsigned long long*>(aorow + dbase) = pk.ll;
        }
    }
}

// ---------- GEMM2: out = ao @ W_out + b_out, BM=64 BN=128 ----------
// R13: 2D-chunked XCD swizzle (16-row x 4-col rectangles of the 64x8 grid).
__global__ __launch_bounds__(256) void gemm_out(const u16* __restrict__ ao,   // [4096][1024]
                                                const u16* __restrict__ wT,   // [1024][1024]
                                                const float* __restrict__ bias,
                                                float* __restrict__ out) {
    __shared__ u16 As[64 * 64];
    __shared__ u16 Bs[128 * 64];
    const int id = blockIdx.y * 8 + blockIdx.x;
    const int xcd = id & 7, pos = id >> 3;       // 64 blocks per XCD
    const int xr = xcd >> 1, xc = xcd & 1;       // 4 row-groups x 2 col-groups
    const int pr = pos >> 2, pc = pos & 3;       // 16 x 4 rectangle
    const int m0 = (xr * 16 + pr) * 64;          // 64 rows
    const int n0 = (xc * 4 + pc) * 128;          // 8 cols
    const int tid = threadIdx.x;
    const int w = tid >> 6, lane = tid & 63, lr = lane & 15, h = lane >> 4;
    f32x4 acc[4][2] = {};

    for (int k0 = 0; k0 < 1024; k0 += 64) {
        __syncthreads();
#pragma unroll
        for (int j = 0; j < 2; ++j) {
            int L = j * 256 + tid;
            int r = L >> 3, c = L & 7;
            gld16(ao + (size_t)(m0 + r) * 1024 + k0 + ((c ^ (r & 7)) << 3), As + L * 8);
        }
#pragma unroll
        for (int j = 0; j < 4; ++j) {
            int L = j * 256 + tid;
            int r = L >> 3, c = L & 7;
            gld16(wT + (size_t)(n0 + r) * 1024 + k0 + ((c ^ (r & 7)) << 3), Bs + L * 8);
        }
        __syncthreads();
#pragma unroll
        for (int kk = 0; kk < 2; ++kk) {
            bf16x8 a[4], b[2];
            int cc = kk * 4 + h;
#pragma unroll
            for (int m = 0; m < 4; ++m) {
                int R = m * 16 + lr;
                a[m] = *reinterpret_cast<const bf16x8*>((const char*)As + R * 128 + ((cc ^ (R & 7)) << 4));
            }
#pragma unroll
            for (int n = 0; n < 2; ++n) {
                int R = w * 32 + n * 16 + lr;
                b[n] = *reinterpret_cast<const bf16x8*>((const char*)Bs + R * 128 + ((cc ^ (R & 7)) << 4));
            }
#pragma unroll
            for (int m = 0; m < 4; ++m)
#pragma unroll
                for (int n = 0; n < 2; ++n)
                    acc[m][n] = __builtin_amdgcn_mfma_f32_16x16x32_bf16(a[m], b[n], acc[m][n], 0, 0, 0);
        }
    }

#pragma unroll
    for (int n = 0; n < 2; ++n) {
        int ng = n0 + w * 32 + n * 16 + lr;
        float bv = bias[ng];
#pragma unroll
        for (int m = 0; m < 4; ++m) {
#pragma unroll
            for (int reg = 0; reg < 4; ++reg) {
                int mg = m0 + m * 16 + h * 4 + reg;
                out[(size_t)mg * 1024 + ng] = acc[m][n][reg] + bv;
            }
        }
    }
}

extern "C" void kernel_launch(void* const* d_in, const int* in_sizes, int n_in,
                              void* d_out, int out_size, void* d_ws, size_t ws_size,
                              hipStream_t stream) {
    const float* x     = (const float*)d_in[0];
    const float* W_qkv = (const float*)d_in[1];
    const float* b_qkv = (const float*)d_in[2];
    const float* W_out = (const float*)d_in[3];
    const float* b_out = (const float*)d_in[4];
    float* out = (float*)d_out;

    char* ws = (char*)d_ws;
    u16* xb    = (u16*)(ws);                       // 8 MB  x bf16 [4096][1024]
    u16* wqkvT = (u16*)(ws + (size_t)( 8u << 20)); // 6 MB  W_qkv^T bf16 [3072][1024]
    u16* woutT = (u16*)(ws + (size_t)(14u << 20)); // 2 MB  W_out^T bf16 [1024][1024]
    u16* qg    = (u16*)(ws + (size_t)(16u << 20)); // 8 MB  Q [B,H,T,D] (pre-scaled)
    u16* kg    = (u16*)(ws + (size_t)(24u << 20)); // 8 MB  K [B,H,T,D]
    u16* vtg   = (u16*)(ws + (size_t)(32u << 20)); // 8 MB  V^T [B,H,D,T] key-permuted
    u16* ao    = xb;                               // reuse x buffer for attn-out

    hipLaunchKernelGGL(prep, dim3(5120), dim3(256), 0, stream, x, xb, W_qkv, wqkvT, W_out, woutT);
    hipLaunchKernelGGL(gemm_qkv, dim3(24, 32), dim3(256), 0, stream, xb, wqkvT, b_qkv, qg, kg, vtg);
    hipLaunchKernelGGL(attn, dim3(32, 16), dim3(256), 0, stream, qg, kg, vtg, ao);
    hipLaunchKernelGGL(gemm_out, dim3(8, 64), dim3(256), 0, stream, ao, woutT, b_out, out);
}

// Round 14
// 110.133 us; speedup vs baseline: 1.1719x; 1.0703x over previous
//
#include <hip/hip_runtime.h>
#include <hip/hip_bf16.h>

// B=2, T=2048, C=1024, H=16, D=64
#define TB 2048
#define CC 1024
#define HH 16
#define DD 64
#define MM 4096     // B*T
#define N3 3072     // 3*C
#define KVB 128
#define NT (TB / KVB)   // 16

typedef __bf16 bf16x8 __attribute__((ext_vector_type(8)));
typedef float f32x4 __attribute__((ext_vector_type(4)));
typedef float f32x16 __attribute__((ext_vector_type(16)));
typedef unsigned short ushort8 __attribute__((ext_vector_type(8)));
typedef unsigned short u16;

// q pre-scale: 0.125 * log2(e)  (softmax done in exp2 domain)
#define QSCALE 0.180336880693612f

__device__ __forceinline__ u16 f2b(float f) {
    unsigned int x = __float_as_uint(f);
    x = (x + 0x7fffu + ((x >> 16) & 1u)) >> 16;
    return (u16)x;
}

__device__ __forceinline__ unsigned cvt_pk_bf16(float lo, float hi) {
    unsigned r;
    asm("v_cvt_pk_bf16_f32 %0, %1, %2" : "=v"(r) : "v"(lo), "v"(hi));
    return r;
}

__device__ __forceinline__ void gld16(const u16* g, u16* l) {
    __builtin_amdgcn_global_load_lds(
        (const __attribute__((address_space(1))) unsigned int*)g,
        (__attribute__((address_space(3))) unsigned int*)l, 16, 0, 0);
}

// ---------- merged prep: fp32->bf16 convert (x) + both weight transposes ----------
__global__ __launch_bounds__(256) void prep(const float* __restrict__ x,
                                            u16* __restrict__ xb,
                                            const float* __restrict__ wqkv,
                                            u16* __restrict__ wqkvT,
                                            const float* __restrict__ wout,
                                            u16* __restrict__ woutT) {
    __shared__ float tl[64][65];
    const int bx = blockIdx.x;
    const int tid = threadIdx.x;
    if (bx < 4096) {
        int i = (bx * 256 + tid) * 4;
        float4 v = *reinterpret_cast<const float4*>(x + i);
        union { u16 u[4]; uint2 v2; } r;
        r.u[0] = f2b(v.x); r.u[1] = f2b(v.y); r.u[2] = f2b(v.z); r.u[3] = f2b(v.w);
        *reinterpret_cast<uint2*>(xb + i) = r.v2;
        return;
    }
    const int idx = bx - 4096;              // 0..1023
    const int nb = idx & 63, kb = idx >> 6; // n-tile, k-tile
    const float* in; u16* out; int N, n0;
    if (nb < 48) { in = wqkv; out = wqkvT; N = 3072; n0 = nb * 64; }
    else         { in = wout; out = woutT; N = 1024; n0 = (nb - 48) * 64; }
    const int k0 = kb * 64;
#pragma unroll
    for (int rep = 0; rep < 16; ++rep) {
        int id2 = rep * 256 + tid;
        int r = id2 >> 6, c = id2 & 63;
        tl[r][c] = in[(size_t)(k0 + r) * N + n0 + c];
    }
    __syncthreads();
#pragma unroll
    for (int rep = 0; rep < 16; ++rep) {
        int id2 = rep * 256 + tid;
        int r = id2 >> 6, c = id2 & 63;
        out[(size_t)(n0 + r) * 1024 + k0 + c] = f2b(tl[c][r]);
    }
}

// ---------- GEMM1: 256x256 tile, BK=64, 8-phase counted-vmcnt schedule ----------
// T2 (conflict-free XOR-swizzled LDS) + T3/T4 (8 phases, vmcnt(4) only at
// p0/p4, loads stay in flight across barriers) + T5 (setprio around MFMA).
// 8 waves (2M x 4N), per-wave C = 128x64, B-frags register-resident per tile.
// V third written key-PERMUTED (swap bits 2<->3 within 16-token blocks).
__global__ __launch_bounds__(512, 2) void gemm_qkv(const u16* __restrict__ xb,   // [4096][1024]
                                                   const u16* __restrict__ wT,   // [3072][1024]
                                                   const float* __restrict__ bias,
                                                   u16* __restrict__ qg,
                                                   u16* __restrict__ kg,
                                                   u16* __restrict__ vtg) {
    __shared__ u16 smem[65536];          // 128 KB: A0|B0|A1|B1 (32KB each)
    u16* const A0 = smem;
    u16* const B0 = smem + 16384;
    u16* const A1 = smem + 32768;
    u16* const B1 = smem + 49152;
    const int id = blockIdx.y * 12 + blockIdx.x;
    const int xcd = id & 7, pos = id >> 3;       // 24 blocks per XCD
    const int m0 = ((xcd >> 1) * 4 + pos / 6) * 256;   // 16 row-tiles
    const int n0 = ((xcd & 1) * 6 + pos % 6) * 256;    // 12 col-tiles
    const int tid = threadIdx.x;
    const int w = tid >> 6, lane = tid & 63, lr = lane & 15, h = lane >> 4;
    const int wr = w >> 2, wc = w & 3;
    f32x4 acc[8][4] = {};
    bf16x8 bB[4][2];
    bf16x8 a[2][2];

#define STAGE_SIDE(dstb, srcp, rowbase, kt) do {                                      \
    _Pragma("unroll")                                                                 \
    for (int jj = 0; jj < 4; ++jj) {                                                  \
        int L = jj * 512 + tid;                                                       \
        int rr = L >> 3, c8 = L & 7;                                                  \
        gld16((srcp) + (size_t)((rowbase) + rr) * 1024 + (kt) * 64                    \
                  + ((c8 ^ (rr & 7)) << 3),                                           \
              (dstb) + L * 8);                                                        \
    } } while (0)
#define DSREAD_B(PB) do {                                                             \
    _Pragma("unroll")                                                                 \
    for (int n = 0; n < 4; ++n) {                                                     \
        int R = wc * 64 + n * 16 + lr;                                                \
        const char* br = (const char*)(PB) + R * 128;                                 \
        bB[n][0] = *reinterpret_cast<const bf16x8*>(br + ((h ^ (R & 7)) << 4));       \
        bB[n][1] = *reinterpret_cast<const bf16x8*>(br + (((4 + h) ^ (R & 7)) << 4)); \
    } } while (0)
#define DSREAD_A(PA, mb) do {                                                         \
    _Pragma("unroll")                                                                 \
    for (int mi = 0; mi < 2; ++mi) {                                                  \
        int R = wr * 128 + ((mb) + mi) * 16 + lr;                                     \
        const char* ar = (const char*)(PA) + R * 128;                                 \
        a[mi][0] = *reinterpret_cast<const bf16x8*>(ar + ((h ^ (R & 7)) << 4));       \
        a[mi][1] = *reinterpret_cast<const bf16x8*>(ar + (((4 + h) ^ (R & 7)) << 4)); \
    } } while (0)
#define MFMAP(mb) do {                                                                \
    _Pragma("unroll")                                                                 \
    for (int mi = 0; mi < 2; ++mi)                                                    \
        _Pragma("unroll")                                                             \
        for (int n = 0; n < 4; ++n) {                                                 \
            acc[(mb) + mi][n] = __builtin_amdgcn_mfma_f32_16x16x32_bf16(              \
                a[mi][0], bB[n][0], acc[(mb) + mi][n], 0, 0, 0);                      \
            acc[(mb) + mi][n] = __builtin_amdgcn_mfma_f32_16x16x32_bf16(              \
                a[mi][1], bB[n][1], acc[(mb) + mi][n], 0, 0, 0);                      \
        } } while (0)
#define GBAR __builtin_amdgcn_s_barrier()
#define VMC(n) asm volatile("s_waitcnt vmcnt(" #n ")" ::: "memory")
#define LGK0 do { asm volatile("s_waitcnt lgkmcnt(0)" ::: "memory");                  \
                  __builtin_amdgcn_sched_barrier(0); } while (0)
#define PRI1 __builtin_amdgcn_s_setprio(1)
#define PRI0 __builtin_amdgcn_s_setprio(0)

    // prologue: tile 0 into parity0 (8 loads outstanding)
    STAGE_SIDE(A0, xb, m0, 0);
    STAGE_SIDE(B0, wT, n0, 0);

#pragma unroll 1
    for (int i = 0; i < 7; ++i) {
        const int t1 = 2 * i + 1, t2 = 2 * i + 2;
        // p0: stage t1.A; wait even tile landed (8 oldest), certify, compute m0-1
        STAGE_SIDE(A1, xb, m0, t1);
        VMC(4); GBAR;
        DSREAD_B(B0); DSREAD_A(A0, 0); LGK0;
        PRI1; MFMAP(0); PRI0; GBAR;
        // p1: stage t1.B
        STAGE_SIDE(B1, wT, n0, t1);
        DSREAD_A(A0, 2); GBAR; LGK0; PRI1; MFMAP(2); PRI0; GBAR;
        // p2
        DSREAD_A(A0, 4); GBAR; LGK0; PRI1; MFMAP(4); PRI0; GBAR;
        // p3
        DSREAD_A(A0, 6); GBAR; LGK0; PRI1; MFMAP(6); PRI0; GBAR;
        // p4: stage t2.A (A0 free after p3); wait odd tile (t1) landed
        STAGE_SIDE(A0, xb, m0, t2);
        VMC(4); GBAR;
        DSREAD_B(B1); DSREAD_A(A1, 0); LGK0;
        PRI1; MFMAP(0); PRI0; GBAR;
        // p5: stage t2.B
        STAGE_SIDE(B0, wT, n0, t2);
        DSREAD_A(A1, 2); GBAR; LGK0; PRI1; MFMAP(2); PRI0; GBAR;
        // p6
        DSREAD_A(A1, 4); GBAR; LGK0; PRI1; MFMAP(4); PRI0; GBAR;
        // p7
        DSREAD_A(A1, 6); GBAR; LGK0; PRI1; MFMAP(6); PRI0; GBAR;
    }
    // peeled final iteration: tiles 14 (parity0), 15 (parity1)
    STAGE_SIDE(A1, xb, m0, 15);
    VMC(4); GBAR;
    DSREAD_B(B0); DSREAD_A(A0, 0); LGK0;
    PRI1; MFMAP(0); PRI0; GBAR;
    STAGE_SIDE(B1, wT, n0, 15);
    DSREAD_A(A0, 2); GBAR; LGK0; PRI1; MFMAP(2); PRI0; GBAR;
    DSREAD_A(A0, 4); GBAR; LGK0; PRI1; MFMAP(4); PRI0; GBAR;
    DSREAD_A(A0, 6); GBAR; LGK0; PRI1; MFMAP(6); PRI0; GBAR;
    VMC(0); GBAR;
    DSREAD_B(B1); DSREAD_A(A1, 0); LGK0;
    PRI1; MFMAP(0); PRI0; GBAR;
    DSREAD_A(A1, 2); GBAR; LGK0; PRI1; MFMAP(2); PRI0; GBAR;
    DSREAD_A(A1, 4); GBAR; LGK0; PRI1; MFMAP(4); PRI0; GBAR;
    DSREAD_A(A1, 6); GBAR; LGK0; PRI1; MFMAP(6); PRI0; GBAR;

#undef STAGE_SIDE
#undef DSREAD_B
#undef DSREAD_A
#undef MFMAP
#undef GBAR
#undef VMC
#undef LGK0
#undef PRI1
#undef PRI0

    // ---------------- epilogue: C through 128KB LDS ----------------
    const int nthird = n0 >> 10;                 // uniform (256 | 1024)
    const int b = m0 >> 11, t0 = m0 & 2047;
    float bv[4];
#pragma unroll
    for (int n = 0; n < 4; ++n)
        bv[n] = bias[n0 + wc * 64 + n * 16 + lr];

    __syncthreads();
    if (nthird == 2) {
        // V: LDS[nloc 256][512B of permuted tokens], slot-swizzled
#pragma unroll
        for (int n = 0; n < 4; ++n) {
            int nloc = wc * 64 + n * 16 + lr;
#pragma unroll
            for (int m = 0; m < 8; ++m) {
                int mloc = wr * 128 + m * 16 + h * 4;
                int mpb = (mloc & ~15) | ((mloc & 4) << 1) | ((mloc & 8) >> 1);
                union { u16 u[4]; unsigned long long ll; } pk4;
#pragma unroll
                for (int reg = 0; reg < 4; ++reg)
                    pk4.u[reg] = f2b(acc[m][n][reg] + bv[n]);
                int slot = mpb >> 3;
                *reinterpret_cast<unsigned long long*>(
                    (char*)smem + nloc * 512 + (((slot ^ (nloc & 31)) << 4) | ((mpb & 7) * 2))) = pk4.ll;
            }
        }
        __syncthreads();
#pragma unroll
        for (int pass = 0; pass < 16; ++pass) {
            int cid = pass * 512 + tid;
            int r = cid >> 5, p = cid & 31;
            ushort8 vch = *reinterpret_cast<const ushort8*>((const char*)smem + r * 512 + (p << 4));
            int tb = p ^ (r & 31);
            int c1 = (n0 & 1023) + r;
            int hh = c1 >> 6, dd = c1 & 63;
            *reinterpret_cast<ushort8*>(
                vtg + ((size_t)(b * HH + hh) * DD + dd) * TB + t0 + tb * 8) = vch;
        }
    } else {
        // Q/K: LDS[row 256][512B of cols], slot-swizzled, coalesced re-read
        const float qs = (nthird == 0) ? QSCALE : 1.0f;
#pragma unroll
        for (int m = 0; m < 8; ++m) {
            int rb = wr * 128 + m * 16 + h * 4;
#pragma unroll
            for (int n = 0; n < 4; ++n) {
                int c = wc * 64 + n * 16 + lr;
#pragma unroll
                for (int reg = 0; reg < 4; ++reg) {
                    int r = rb + reg;
                    *reinterpret_cast<u16*>((char*)smem + r * 512 +
                        ((((c >> 3) ^ (r & 31)) << 4) | ((c & 7) << 1)))
                        = f2b((acc[m][n][reg] + bv[n]) * qs);
                }
            }
        }
        __syncthreads();
        u16* dst = (nthird == 0) ? qg : kg;
#pragma unroll
        for (int pass = 0; pass < 16; ++pass) {
            int cid = pass * 512 + tid;
            int r = cid >> 5, p = cid & 31;
            ushort8 vch = *reinterpret_cast<const ushort8*>((const char*)smem + r * 512 + (p << 4));
            int cb = p ^ (r & 31);
            int c1 = (n0 & 1023) + cb * 8;
            int hh = c1 >> 6, dd = c1 & 63;
            *reinterpret_cast<ushort8*>(
                dst + ((size_t)(b * HH + hh) * TB + t0 + r) * DD + dd) = vch;
        }
    }
}

// ---------- flash attention: 4 waves x 32 q-rows, 32x32x16 MFMA, KVB=128 ----------
// (R12/R13-proven; 52.8 us.)
__global__ __launch_bounds__(256, 2) void attn(const u16* __restrict__ qg,
                                               const u16* __restrict__ kg,
                                               const u16* __restrict__ vtg,
                                               u16* __restrict__ ao) {
    __shared__ u16 Kt[2][KVB * 64];   // [key][d], 128B rows, XOR-swizzled
    __shared__ u16 Vt[2][64 * KVB];   // [d][key-permuted], 256B rows, XOR-swizzled
    const int bh = blockIdx.x;
    const int q0 = blockIdx.y * 128;
    const int tid = threadIdx.x, w = tid >> 6, lane = tid & 63;
    const int ln = lane & 31, H = lane >> 5;
    const u16* qb = qg + (size_t)bh * TB * DD;
    const u16* kb = kg + (size_t)bh * TB * DD;
    const u16* vb = vtg + (size_t)bh * DD * TB;

#define STAGE(buf, kp, vp) do {                                                         \
    _Pragma("unroll")                                                                   \
    for (int j = 0; j < 4; ++j) {                                                       \
        int L = j * 256 + tid;                                                          \
        int rk = L >> 3, ck = L & 7;                                                    \
        gld16((kp) + (size_t)rk * DD + ((ck ^ (rk & 7)) << 3), Kt[buf] + L * 8);        \
        int rv = L >> 4, cv = L & 15;                                                   \
        gld16((vp) + (size_t)rv * TB + ((cv ^ (rv & 15)) << 3), Vt[buf] + L * 8);       \
    } } while (0)

    bf16x8 bq[4];        // Q[q=ln][d = dc*16 + H*8 + j]
#pragma unroll
    for (int dc = 0; dc < 4; ++dc)
        bq[dc] = *reinterpret_cast<const bf16x8*>(
            qb + (size_t)(q0 + w * 32 + ln) * DD + dc * 16 + H * 8);

    f32x16 o[2] = {};     // O^T[d = ngd*32+(reg&3)+8*(reg>>2)+4H][q=ln]
    float m_r = -1e30f;
    float l_r = 0.f;
    f32x16 zero16 = {};

    auto tile_body = [&](const u16* ktc, const u16* vtc) {
        // S^T = K Q^T : s[kb4] reg r -> S[key = kb4*32+(r&3)+8*(r>>2)+4H][q=ln]
        f32x16 s[4];
        __builtin_amdgcn_s_setprio(1);
#pragma unroll
        for (int kb4 = 0; kb4 < 4; ++kb4) {
            int R = kb4 * 32 + ln;
            const char* krow = (const char*)ktc + R * 128;
#pragma unroll
            for (int dc = 0; dc < 4; ++dc) {
                bf16x8 ak = *reinterpret_cast<const bf16x8*>(
                    krow + (((dc * 2 + H) ^ (R & 7)) << 4));
                s[kb4] = __builtin_amdgcn_mfma_f32_32x32x16_bf16(
                    ak, bq[dc], dc == 0 ? zero16 : s[kb4], 0, 0, 0);
            }
        }
        __builtin_amdgcn_s_setprio(0);

        // online softmax (exp2 domain), defer-max; fully lane-local
        float pm = s[0][0];
#pragma unroll
        for (int kb4 = 0; kb4 < 4; ++kb4) {
            float t0 = fmaxf(fmaxf(s[kb4][0], s[kb4][1]), fmaxf(s[kb4][2], s[kb4][3]));
            float t1 = fmaxf(fmaxf(s[kb4][4], s[kb4][5]), fmaxf(s[kb4][6], s[kb4][7]));
            float t2 = fmaxf(fmaxf(s[kb4][8], s[kb4][9]), fmaxf(s[kb4][10], s[kb4][11]));
            float t3 = fmaxf(fmaxf(s[kb4][12], s[kb4][13]), fmaxf(s[kb4][14], s[kb4][15]));
            pm = fmaxf(pm, fmaxf(fmaxf(t0, t1), fmaxf(t2, t3)));
        }
        pm = fmaxf(pm, __shfl_xor(pm, 32));

        if (!__all(pm - m_r <= 8.0f)) {
            float mn = fmaxf(m_r, pm);
            float fr = __builtin_amdgcn_exp2f(m_r - mn);
            m_r = mn;
            l_r *= fr;
#pragma unroll
            for (int ngd = 0; ngd < 2; ++ngd)
#pragma unroll
                for (int r = 0; r < 16; ++r)
                    o[ngd][r] *= fr;
        }

        float sum = 0.f;
#pragma unroll
        for (int kb4 = 0; kb4 < 4; ++kb4) {
            float ps = 0.f;
#pragma unroll
            for (int r = 0; r < 16; ++r) {
                s[kb4][r] = __builtin_amdgcn_exp2f(s[kb4][r] - m_r);
                ps += s[kb4][r];
            }
            sum += ps;
        }
        sum += __shfl_xor(sum, 32);
        l_r += sum;

        // O^T += V^T P^T ; V keys permuted so B-frag is the lane's own regs
        __builtin_amdgcn_s_setprio(1);
#pragma unroll
        for (int kb4 = 0; kb4 < 4; ++kb4) {
#pragma unroll
            for (int b1 = 0; b1 < 2; ++b1) {
                union { unsigned u[4]; bf16x8 v; } ap;
                ap.u[0] = cvt_pk_bf16(s[kb4][8 * b1 + 0], s[kb4][8 * b1 + 1]);
                ap.u[1] = cvt_pk_bf16(s[kb4][8 * b1 + 2], s[kb4][8 * b1 + 3]);
                ap.u[2] = cvt_pk_bf16(s[kb4][8 * b1 + 4], s[kb4][8 * b1 + 5]);
                ap.u[3] = cvt_pk_bf16(s[kb4][8 * b1 + 6], s[kb4][8 * b1 + 7]);
                int c = kb4 * 2 + b1;
#pragma unroll
                for (int ngd = 0; ngd < 2; ++ngd) {
                    int d = ngd * 32 + ln;
                    bf16x8 av = *reinterpret_cast<const bf16x8*>(
                        (const char*)vtc + d * 256 + (((c * 2 + H) ^ (d & 15)) << 4));
                    o[ngd] = __builtin_amdgcn_mfma_f32_32x32x16_bf16(av, ap.v, o[ngd], 0, 0, 0);
                }
            }
        }
        __builtin_amdgcn_s_setprio(0);
    };

    STAGE(0, kb, vb);
    const u16* kp = kb + KVB * DD;
    const u16* vp = vb + KVB;
    __syncthreads();

#pragma unroll 1
    for (int kt2 = 0; kt2 < NT / 2; ++kt2) {
        STAGE(1, kp, vp);
        kp += KVB * DD; vp += KVB;
        tile_body(Kt[0], Vt[0]);
        __syncthreads();
        if (kt2 < NT / 2 - 1) {
            STAGE(0, kp, vp);
            kp += KVB * DD; vp += KVB;
        }
        tile_body(Kt[1], Vt[1]);
        __syncthreads();
    }
#undef STAGE

    const float linv = 1.0f / l_r;
    const int b = bh >> 4, hh = bh & 15;
    const int q = q0 + w * 32 + ln;
    u16* aorow = ao + (size_t)(b * TB + q) * CC + hh * 64;
#pragma unroll
    for (int ngd = 0; ngd < 2; ++ngd) {
#pragma unroll
        for (int rg = 0; rg < 4; ++rg) {
            int dbase = ngd * 32 + 8 * rg + 4 * H;
            union { u16 u[4]; unsigned long long ll; } pk;
#pragma unroll
            for (int r2 = 0; r2 < 4; ++r2)
                pk.u[r2] = f2b(o[ngd][4 * rg + r2] * linv);
            *reinterpret_cast<unsigned long long*>(aorow + dbase) = pk.ll;
        }
    }
}

// ---------- GEMM2: out = ao @ W_out + b_out, BM=64 BN=128 ----------
// (R13-proven; 2D-chunked XCD swizzle.)
__global__ __launch_bounds__(256) void gemm_out(const u16* __restrict__ ao,   // [4096][1024]
                                                const u16* __restrict__ wT,   // [1024][1024]
                                                const float* __restrict__ bias,
                                                float* __restrict__ out) {
    __shared__ u16 As[64 * 64];
    __shared__ u16 Bs[128 * 64];
    const int id = blockIdx.y * 8 + blockIdx.x;
    const int xcd = id & 7, pos = id >> 3;       // 64 blocks per XCD
    const int xr = xcd >> 1, xc = xcd & 1;       // 4 row-groups x 2 col-groups
    const int pr = pos >> 2, pc = pos & 3;       // 16 x 4 rectangle
    const int m0 = (xr * 16 + pr) * 64;          // 64 rows
    const int n0 = (xc * 4 + pc) * 128;          // 8 cols
    const int tid = threadIdx.x;
    const int w = tid >> 6, lane = tid & 63, lr = lane & 15, h = lane >> 4;
    f32x4 acc[4][2] = {};

    for (int k0 = 0; k0 < 1024; k0 += 64) {
        __syncthreads();
#pragma unroll
        for (int j = 0; j < 2; ++j) {
            int L = j * 256 + tid;
            int r = L >> 3, c = L & 7;
            gld16(ao + (size_t)(m0 + r) * 1024 + k0 + ((c ^ (r & 7)) << 3), As + L * 8);
        }
#pragma unroll
        for (int j = 0; j < 4; ++j) {
            int L = j * 256 + tid;
            int r = L >> 3, c = L & 7;
            gld16(wT + (size_t)(n0 + r) * 1024 + k0 + ((c ^ (r & 7)) << 3), Bs + L * 8);
        }
        __syncthreads();
#pragma unroll
        for (int kk = 0; kk < 2; ++kk) {
            bf16x8 a[4], b[2];
            int cc = kk * 4 + h;
#pragma unroll
            for (int m = 0; m < 4; ++m) {
                int R = m * 16 + lr;
                a[m] = *reinterpret_cast<const bf16x8*>((const char*)As + R * 128 + ((cc ^ (R & 7)) << 4));
            }
#pragma unroll
            for (int n = 0; n < 2; ++n) {
                int R = w * 32 + n * 16 + lr;
                b[n] = *reinterpret_cast<const bf16x8*>((const char*)Bs + R * 128 + ((cc ^ (R & 7)) << 4));
            }
#pragma unroll
            for (int m = 0; m < 4; ++m)
#pragma unroll
                for (int n = 0; n < 2; ++n)
                    acc[m][n] = __builtin_amdgcn_mfma_f32_16x16x32_bf16(a[m], b[n], acc[m][n], 0, 0, 0);
        }
    }

#pragma unroll
    for (int n = 0; n < 2; ++n) {
        int ng = n0 + w * 32 + n * 16 + lr;
        float bv = bias[ng];
#pragma unroll
        for (int m = 0; m < 4; ++m) {
#pragma unroll
            for (int reg = 0; reg < 4; ++reg) {
                int mg = m0 + m * 16 + h * 4 + reg;
                out[(size_t)mg * 1024 + ng] = acc[m][n][reg] + bv;
            }
        }
    }
}

extern "C" void kernel_launch(void* const* d_in, const int* in_sizes, int n_in,
                              void* d_out, int out_size, void* d_ws, size_t ws_size,
                              hipStream_t stream) {
    const float* x     = (const float*)d_in[0];
    const float* W_qkv = (const float*)d_in[1];
    const float* b_qkv = (const float*)d_in[2];
    const float* W_out = (const float*)d_in[3];
    const float* b_out = (const float*)d_in[4];
    float* out = (float*)d_out;

    char* ws = (char*)d_ws;
    u16* xb    = (u16*)(ws);                       // 8 MB  x bf16 [4096][1024]
    u16* wqkvT = (u16*)(ws + (size_t)( 8u << 20)); // 6 MB  W_qkv^T bf16 [3072][1024]
    u16* woutT = (u16*)(ws + (size_t)(14u << 20)); // 2 MB  W_out^T bf16 [1024][1024]
    u16* qg    = (u16*)(ws + (size_t)(16u << 20)); // 8 MB  Q [B,H,T,D] (pre-scaled)
    u16* kg    = (u16*)(ws + (size_t)(24u << 20)); // 8 MB  K [B,H,T,D]
    u16* vtg   = (u16*)(ws + (size_t)(32u << 20)); // 8 MB  V^T [B,H,D,T] key-permuted
    u16* ao    = xb;                               // reuse x buffer for attn-out

    hipLaunchKernelGGL(prep, dim3(5120), dim3(256), 0, stream, x, xb, W_qkv, wqkvT, W_out, woutT);
    hipLaunchKernelGGL(gemm_qkv, dim3(12, 16), dim3(512), 0, stream, xb, wqkvT, b_qkv, qg, kg, vtg);
    hipLaunchKernelGGL(attn, dim3(32, 16), dim3(256), 0, stream, qg, kg, vtg, ao);
    hipLaunchKernelGGL(gemm_out, dim3(8, 64), dim3(256), 0, stream, ao, woutT, b_out, out);
}

// Round 15
// 109.831 us; speedup vs baseline: 1.1751x; 1.0027x over previous
//
#include <hip/hip_runtime.h>
#include <hip/hip_bf16.h>

// B=2, T=2048, C=1024, H=16, D=64
#define TB 2048
#define CC 1024
#define HH 16
#define DD 64
#define MM 4096     // B*T
#define N3 3072     // 3*C
#define KVB 128
#define NT (TB / KVB)   // 16

typedef __bf16 bf16x8 __attribute__((ext_vector_type(8)));
typedef float f32x4 __attribute__((ext_vector_type(4)));
typedef float f32x16 __attribute__((ext_vector_type(16)));
typedef unsigned short ushort8 __attribute__((ext_vector_type(8)));
typedef unsigned short u16;

// q pre-scale: 0.125 * log2(e)  (softmax done in exp2 domain)
#define QSCALE 0.180336880693612f

__device__ __forceinline__ u16 f2b(float f) {
    unsigned int x = __float_as_uint(f);
    x = (x + 0x7fffu + ((x >> 16) & 1u)) >> 16;
    return (u16)x;
}

__device__ __forceinline__ unsigned cvt_pk_bf16(float lo, float hi) {
    unsigned r;
    asm("v_cvt_pk_bf16_f32 %0, %1, %2" : "=v"(r) : "v"(lo), "v"(hi));
    return r;
}

__device__ __forceinline__ void gld16(const u16* g, u16* l) {
    __builtin_amdgcn_global_load_lds(
        (const __attribute__((address_space(1))) unsigned int*)g,
        (__attribute__((address_space(3))) unsigned int*)l, 16, 0, 0);
}

// ---------- merged prep: fp32->bf16 convert (x) + both weight transposes ----------
// R15: transpose tile loads as float4, stores as packed 8B (was 4B loads / 2B stores).
__global__ __launch_bounds__(256) void prep(const float* __restrict__ x,
                                            u16* __restrict__ xb,
                                            const float* __restrict__ wqkv,
                                            u16* __restrict__ wqkvT,
                                            const float* __restrict__ wout,
                                            u16* __restrict__ woutT) {
    __shared__ float tl[64][65];
    const int bx = blockIdx.x;
    const int tid = threadIdx.x;
    if (bx < 4096) {
        int i = (bx * 256 + tid) * 4;
        float4 v = *reinterpret_cast<const float4*>(x + i);
        union { u16 u[4]; uint2 v2; } r;
        r.u[0] = f2b(v.x); r.u[1] = f2b(v.y); r.u[2] = f2b(v.z); r.u[3] = f2b(v.w);
        *reinterpret_cast<uint2*>(xb + i) = r.v2;
        return;
    }
    const int idx = bx - 4096;              // 0..1023
    const int nb = idx & 63, kb = idx >> 6; // n-tile, k-tile
    const float* in; u16* out; int N, n0;
    if (nb < 48) { in = wqkv; out = wqkvT; N = 3072; n0 = nb * 64; }
    else         { in = wout; out = woutT; N = 1024; n0 = (nb - 48) * 64; }
    const int k0 = kb * 64;
#pragma unroll
    for (int rep = 0; rep < 4; ++rep) {
        int r = rep * 16 + (tid >> 4);
        int c4 = (tid & 15) * 4;
        float4 v = *reinterpret_cast<const float4*>(&in[(size_t)(k0 + r) * N + n0 + c4]);
        tl[r][c4] = v.x; tl[r][c4 + 1] = v.y; tl[r][c4 + 2] = v.z; tl[r][c4 + 3] = v.w;
    }
    __syncthreads();
#pragma unroll
    for (int rep = 0; rep < 4; ++rep) {
        int nn = rep * 16 + (tid >> 4);
        int kk4 = (tid & 15) * 4;
        union { u16 u[4]; unsigned long long ll; } pk;
#pragma unroll
        for (int i = 0; i < 4; ++i)
            pk.u[i] = f2b(tl[kk4 + i][nn]);
        *reinterpret_cast<unsigned long long*>(&out[(size_t)(n0 + nn) * 1024 + k0 + kk4]) = pk.ll;
    }
}

// ---------- GEMM1: 256x256 tile, BK=64, 8-phase counted-vmcnt schedule ----------
// (R14-proven.) T2 swizzle + T3/T4 (vmcnt(4) at p0/p4 only) + T5 setprio.
// 8 waves (2M x 4N), per-wave C = 128x64, B-frags register-resident per tile.
// V third written key-PERMUTED (swap bits 2<->3 within 16-token blocks).
__global__ __launch_bounds__(512, 2) void gemm_qkv(const u16* __restrict__ xb,   // [4096][1024]
                                                   const u16* __restrict__ wT,   // [3072][1024]
                                                   const float* __restrict__ bias,
                                                   u16* __restrict__ qg,
                                                   u16* __restrict__ kg,
                                                   u16* __restrict__ vtg) {
    __shared__ u16 smem[65536];          // 128 KB: A0|B0|A1|B1 (32KB each)
    u16* const A0 = smem;
    u16* const B0 = smem + 16384;
    u16* const A1 = smem + 32768;
    u16* const B1 = smem + 49152;
    const int id = blockIdx.y * 12 + blockIdx.x;
    const int xcd = id & 7, pos = id >> 3;       // 24 blocks per XCD
    const int m0 = ((xcd >> 1) * 4 + pos / 6) * 256;   // 16 row-tiles
    const int n0 = ((xcd & 1) * 6 + pos % 6) * 256;    // 12 col-tiles
    const int tid = threadIdx.x;
    const int w = tid >> 6, lane = tid & 63, lr = lane & 15, h = lane >> 4;
    const int wr = w >> 2, wc = w & 3;
    f32x4 acc[8][4] = {};
    bf16x8 bB[4][2];
    bf16x8 a[2][2];

#define STAGE_SIDE(dstb, srcp, rowbase, kt) do {                                      \
    _Pragma("unroll")                                                                 \
    for (int jj = 0; jj < 4; ++jj) {                                                  \
        int L = jj * 512 + tid;                                                       \
        int rr = L >> 3, c8 = L & 7;                                                  \
        gld16((srcp) + (size_t)((rowbase) + rr) * 1024 + (kt) * 64                    \
                  + ((c8 ^ (rr & 7)) << 3),                                           \
              (dstb) + L * 8);                                                        \
    } } while (0)
#define DSREAD_B(PB) do {                                                             \
    _Pragma("unroll")                                                                 \
    for (int n = 0; n < 4; ++n) {                                                     \
        int R = wc * 64 + n * 16 + lr;                                                \
        const char* br = (const char*)(PB) + R * 128;                                 \
        bB[n][0] = *reinterpret_cast<const bf16x8*>(br + ((h ^ (R & 7)) << 4));       \
        bB[n][1] = *reinterpret_cast<const bf16x8*>(br + (((4 + h) ^ (R & 7)) << 4)); \
    } } while (0)
#define DSREAD_A(PA, mb) do {                                                         \
    _Pragma("unroll")                                                                 \
    for (int mi = 0; mi < 2; ++mi) {                                                  \
        int R = wr * 128 + ((mb) + mi) * 16 + lr;                                     \
        const char* ar = (const char*)(PA) + R * 128;                                 \
        a[mi][0] = *reinterpret_cast<const bf16x8*>(ar + ((h ^ (R & 7)) << 4));       \
        a[mi][1] = *reinterpret_cast<const bf16x8*>(ar + (((4 + h) ^ (R & 7)) << 4)); \
    } } while (0)
#define MFMAP(mb) do {                                                                \
    _Pragma("unroll")                                                                 \
    for (int mi = 0; mi < 2; ++mi)                                                    \
        _Pragma("unroll")                                                             \
        for (int n = 0; n < 4; ++n) {                                                 \
            acc[(mb) + mi][n] = __builtin_amdgcn_mfma_f32_16x16x32_bf16(              \
                a[mi][0], bB[n][0], acc[(mb) + mi][n], 0, 0, 0);                      \
            acc[(mb) + mi][n] = __builtin_amdgcn_mfma_f32_16x16x32_bf16(              \
                a[mi][1], bB[n][1], acc[(mb) + mi][n], 0, 0, 0);                      \
        } } while (0)
#define GBAR __builtin_amdgcn_s_barrier()
#define VMC(n) asm volatile("s_waitcnt vmcnt(" #n ")" ::: "memory")
#define LGK0 do { asm volatile("s_waitcnt lgkmcnt(0)" ::: "memory");                  \
                  __builtin_amdgcn_sched_barrier(0); } while (0)
#define PRI1 __builtin_amdgcn_s_setprio(1)
#define PRI0 __builtin_amdgcn_s_setprio(0)

    // prologue: tile 0 into parity0 (8 loads outstanding)
    STAGE_SIDE(A0, xb, m0, 0);
    STAGE_SIDE(B0, wT, n0, 0);

#pragma unroll 1
    for (int i = 0; i < 7; ++i) {
        const int t1 = 2 * i + 1, t2 = 2 * i + 2;
        // p0: stage t1.A; wait even tile landed (8 oldest), certify, compute m0-1
        STAGE_SIDE(A1, xb, m0, t1);
        VMC(4); GBAR;
        DSREAD_B(B0); DSREAD_A(A0, 0); LGK0;
        PRI1; MFMAP(0); PRI0; GBAR;
        // p1: stage t1.B
        STAGE_SIDE(B1, wT, n0, t1);
        DSREAD_A(A0, 2); GBAR; LGK0; PRI1; MFMAP(2); PRI0; GBAR;
        // p2
        DSREAD_A(A0, 4); GBAR; LGK0; PRI1; MFMAP(4); PRI0; GBAR;
        // p3
        DSREAD_A(A0, 6); GBAR; LGK0; PRI1; MFMAP(6); PRI0; GBAR;
        // p4: stage t2.A (A0 free after p3); wait odd tile (t1) landed
        STAGE_SIDE(A0, xb, m0, t2);
        VMC(4); GBAR;
        DSREAD_B(B1); DSREAD_A(A1, 0); LGK0;
        PRI1; MFMAP(0); PRI0; GBAR;
        // p5: stage t2.B
        STAGE_SIDE(B0, wT, n0, t2);
        DSREAD_A(A1, 2); GBAR; LGK0; PRI1; MFMAP(2); PRI0; GBAR;
        // p6
        DSREAD_A(A1, 4); GBAR; LGK0; PRI1; MFMAP(4); PRI0; GBAR;
        // p7
        DSREAD_A(A1, 6); GBAR; LGK0; PRI1; MFMAP(6); PRI0; GBAR;
    }
    // peeled final iteration: tiles 14 (parity0), 15 (parity1)
    STAGE_SIDE(A1, xb, m0, 15);
    VMC(4); GBAR;
    DSREAD_B(B0); DSREAD_A(A0, 0); LGK0;
    PRI1; MFMAP(0); PRI0; GBAR;
    STAGE_SIDE(B1, wT, n0, 15);
    DSREAD_A(A0, 2); GBAR; LGK0; PRI1; MFMAP(2); PRI0; GBAR;
    DSREAD_A(A0, 4); GBAR; LGK0; PRI1; MFMAP(4); PRI0; GBAR;
    DSREAD_A(A0, 6); GBAR; LGK0; PRI1; MFMAP(6); PRI0; GBAR;
    VMC(0); GBAR;
    DSREAD_B(B1); DSREAD_A(A1, 0); LGK0;
    PRI1; MFMAP(0); PRI0; GBAR;
    DSREAD_A(A1, 2); GBAR; LGK0; PRI1; MFMAP(2); PRI0; GBAR;
    DSREAD_A(A1, 4); GBAR; LGK0; PRI1; MFMAP(4); PRI0; GBAR;
    DSREAD_A(A1, 6); GBAR; LGK0; PRI1; MFMAP(6); PRI0; GBAR;

#undef STAGE_SIDE
#undef DSREAD_B
#undef DSREAD_A
#undef MFMAP
#undef GBAR
#undef VMC
#undef LGK0
#undef PRI1
#undef PRI0

    // ---------------- epilogue: C through 128KB LDS ----------------
    const int nthird = n0 >> 10;                 // uniform (256 | 1024)
    const int b = m0 >> 11, t0 = m0 & 2047;
    float bv[4];
#pragma unroll
    for (int n = 0; n < 4; ++n)
        bv[n] = bias[n0 + wc * 64 + n * 16 + lr];

    __syncthreads();
    if (nthird == 2) {
        // V: LDS[nloc 256][512B of permuted tokens], slot-swizzled
#pragma unroll
        for (int n = 0; n < 4; ++n) {
            int nloc = wc * 64 + n * 16 + lr;
#pragma unroll
            for (int m = 0; m < 8; ++m) {
                int mloc = wr * 128 + m * 16 + h * 4;
                int mpb = (mloc & ~15) | ((mloc & 4) << 1) | ((mloc & 8) >> 1);
                union { u16 u[4]; unsigned long long ll; } pk4;
#pragma unroll
                for (int reg = 0; reg < 4; ++reg)
                    pk4.u[reg] = f2b(acc[m][n][reg] + bv[n]);
                int slot = mpb >> 3;
                *reinterpret_cast<unsigned long long*>(
                    (char*)smem + nloc * 512 + (((slot ^ (nloc & 31)) << 4) | ((mpb & 7) * 2))) = pk4.ll;
            }
        }
        __syncthreads();
#pragma unroll
        for (int pass = 0; pass < 16; ++pass) {
            int cid = pass * 512 + tid;
            int r = cid >> 5, p = cid & 31;
            ushort8 vch = *reinterpret_cast<const ushort8*>((const char*)smem + r * 512 + (p << 4));
            int tb = p ^ (r & 31);
            int c1 = (n0 & 1023) + r;
            int hh = c1 >> 6, dd = c1 & 63;
            *reinterpret_cast<ushort8*>(
                vtg + ((size_t)(b * HH + hh) * DD + dd) * TB + t0 + tb * 8) = vch;
        }
    } else {
        // Q/K: LDS[row 256][512B of cols], slot-swizzled, coalesced re-read
        const float qs = (nthird == 0) ? QSCALE : 1.0f;
#pragma unroll
        for (int m = 0; m < 8; ++m) {
            int rb = wr * 128 + m * 16 + h * 4;
#pragma unroll
            for (int n = 0; n < 4; ++n) {
                int c = wc * 64 + n * 16 + lr;
#pragma unroll
                for (int reg = 0; reg < 4; ++reg) {
                    int r = rb + reg;
                    *reinterpret_cast<u16*>((char*)smem + r * 512 +
                        ((((c >> 3) ^ (r & 31)) << 4) | ((c & 7) << 1)))
                        = f2b((acc[m][n][reg] + bv[n]) * qs);
                }
            }
        }
        __syncthreads();
        u16* dst = (nthird == 0) ? qg : kg;
#pragma unroll
        for (int pass = 0; pass < 16; ++pass) {
            int cid = pass * 512 + tid;
            int r = cid >> 5, p = cid & 31;
            ushort8 vch = *reinterpret_cast<const ushort8*>((const char*)smem + r * 512 + (p << 4));
            int cb = p ^ (r & 31);
            int c1 = (n0 & 1023) + cb * 8;
            int hh = c1 >> 6, dd = c1 & 63;
            *reinterpret_cast<ushort8*>(
                dst + ((size_t)(b * HH + hh) * TB + t0 + r) * DD + dd) = vch;
        }
    }
}

// ---------- flash attention: 4 waves x 32 q-rows, 32x32x16 MFMA, KVB=128 ----------
// (R12/R13-proven; 52.1 us plateau.)
__global__ __launch_bounds__(256, 2) void attn(const u16* __restrict__ qg,
                                               const u16* __restrict__ kg,
                                               const u16* __restrict__ vtg,
                                               u16* __restrict__ ao) {
    __shared__ u16 Kt[2][KVB * 64];   // [key][d], 128B rows, XOR-swizzled
    __shared__ u16 Vt[2][64 * KVB];   // [d][key-permuted], 256B rows, XOR-swizzled
    const int bh = blockIdx.x;
    const int q0 = blockIdx.y * 128;
    const int tid = threadIdx.x, w = tid >> 6, lane = tid & 63;
    const int ln = lane & 31, H = lane >> 5;
    const u16* qb = qg + (size_t)bh * TB * DD;
    const u16* kb = kg + (size_t)bh * TB * DD;
    const u16* vb = vtg + (size_t)bh * DD * TB;

#define STAGE(buf, kp, vp) do {                                                         \
    _Pragma("unroll")                                                                   \
    for (int j = 0; j < 4; ++j) {                                                       \
        int L = j * 256 + tid;                                                          \
        int rk = L >> 3, ck = L & 7;                                                    \
        gld16((kp) + (size_t)rk * DD + ((ck ^ (rk & 7)) << 3), Kt[buf] + L * 8);        \
        int rv = L >> 4, cv = L & 15;                                                   \
        gld16((vp) + (size_t)rv * TB + ((cv ^ (rv & 15)) << 3), Vt[buf] + L * 8);       \
    } } while (0)

    bf16x8 bq[4];        // Q[q=ln][d = dc*16 + H*8 + j]
#pragma unroll
    for (int dc = 0; dc < 4; ++dc)
        bq[dc] = *reinterpret_cast<const bf16x8*>(
            qb + (size_t)(q0 + w * 32 + ln) * DD + dc * 16 + H * 8);

    f32x16 o[2] = {};     // O^T[d = ngd*32+(reg&3)+8*(reg>>2)+4H][q=ln]
    float m_r = -1e30f;
    float l_r = 0.f;
    f32x16 zero16 = {};

    auto tile_body = [&](const u16* ktc, const u16* vtc) {
        // S^T = K Q^T : s[kb4] reg r -> S[key = kb4*32+(r&3)+8*(r>>2)+4H][q=ln]
        f32x16 s[4];
        __builtin_amdgcn_s_setprio(1);
#pragma unroll
        for (int kb4 = 0; kb4 < 4; ++kb4) {
            int R = kb4 * 32 + ln;
            const char* krow = (const char*)ktc + R * 128;
#pragma unroll
            for (int dc = 0; dc < 4; ++dc) {
                bf16x8 ak = *reinterpret_cast<const bf16x8*>(
                    krow + (((dc * 2 + H) ^ (R & 7)) << 4));
                s[kb4] = __builtin_amdgcn_mfma_f32_32x32x16_bf16(
                    ak, bq[dc], dc == 0 ? zero16 : s[kb4], 0, 0, 0);
            }
        }
        __builtin_amdgcn_s_setprio(0);

        // online softmax (exp2 domain), defer-max; fully lane-local
        float pm = s[0][0];
#pragma unroll
        for (int kb4 = 0; kb4 < 4; ++kb4) {
            float t0 = fmaxf(fmaxf(s[kb4][0], s[kb4][1]), fmaxf(s[kb4][2], s[kb4][3]));
            float t1 = fmaxf(fmaxf(s[kb4][4], s[kb4][5]), fmaxf(s[kb4][6], s[kb4][7]));
            float t2 = fmaxf(fmaxf(s[kb4][8], s[kb4][9]), fmaxf(s[kb4][10], s[kb4][11]));
            float t3 = fmaxf(fmaxf(s[kb4][12], s[kb4][13]), fmaxf(s[kb4][14], s[kb4][15]));
            pm = fmaxf(pm, fmaxf(fmaxf(t0, t1), fmaxf(t2, t3)));
        }
        pm = fmaxf(pm, __shfl_xor(pm, 32));

        if (!__all(pm - m_r <= 8.0f)) {
            float mn = fmaxf(m_r, pm);
            float fr = __builtin_amdgcn_exp2f(m_r - mn);
            m_r = mn;
            l_r *= fr;
#pragma unroll
            for (int ngd = 0; ngd < 2; ++ngd)
#pragma unroll
                for (int r = 0; r < 16; ++r)
                    o[ngd][r] *= fr;
        }

        float sum = 0.f;
#pragma unroll
        for (int kb4 = 0; kb4 < 4; ++kb4) {
            float ps = 0.f;
#pragma unroll
            for (int r = 0; r < 16; ++r) {
                s[kb4][r] = __builtin_amdgcn_exp2f(s[kb4][r] - m_r);
                ps += s[kb4][r];
            }
            sum += ps;
        }
        sum += __shfl_xor(sum, 32);
        l_r += sum;

        // O^T += V^T P^T ; V keys permuted so B-frag is the lane's own regs
        __builtin_amdgcn_s_setprio(1);
#pragma unroll
        for (int kb4 = 0; kb4 < 4; ++kb4) {
#pragma unroll
            for (int b1 = 0; b1 < 2; ++b1) {
                union { unsigned u[4]; bf16x8 v; } ap;
                ap.u[0] = cvt_pk_bf16(s[kb4][8 * b1 + 0], s[kb4][8 * b1 + 1]);
                ap.u[1] = cvt_pk_bf16(s[kb4][8 * b1 + 2], s[kb4][8 * b1 + 3]);
                ap.u[2] = cvt_pk_bf16(s[kb4][8 * b1 + 4], s[kb4][8 * b1 + 5]);
                ap.u[3] = cvt_pk_bf16(s[kb4][8 * b1 + 6], s[kb4][8 * b1 + 7]);
                int c = kb4 * 2 + b1;
#pragma unroll
                for (int ngd = 0; ngd < 2; ++ngd) {
                    int d = ngd * 32 + ln;
                    bf16x8 av = *reinterpret_cast<const bf16x8*>(
                        (const char*)vtc + d * 256 + (((c * 2 + H) ^ (d & 15)) << 4));
                    o[ngd] = __builtin_amdgcn_mfma_f32_32x32x16_bf16(av, ap.v, o[ngd], 0, 0, 0);
                }
            }
        }
        __builtin_amdgcn_s_setprio(0);
    };

    STAGE(0, kb, vb);
    const u16* kp = kb + KVB * DD;
    const u16* vp = vb + KVB;
    __syncthreads();

#pragma unroll 1
    for (int kt2 = 0; kt2 < NT / 2; ++kt2) {
        STAGE(1, kp, vp);
        kp += KVB * DD; vp += KVB;
        tile_body(Kt[0], Vt[0]);
        __syncthreads();
        if (kt2 < NT / 2 - 1) {
            STAGE(0, kp, vp);
            kp += KVB * DD; vp += KVB;
        }
        tile_body(Kt[1], Vt[1]);
        __syncthreads();
    }
#undef STAGE

    const float linv = 1.0f / l_r;
    const int b = bh >> 4, hh = bh & 15;
    const int q = q0 + w * 32 + ln;
    u16* aorow = ao + (size_t)(b * TB + q) * CC + hh * 64;
#pragma unroll
    for (int ngd = 0; ngd < 2; ++ngd) {
#pragma unroll
        for (int rg = 0; rg < 4; ++rg) {
            int dbase = ngd * 32 + 8 * rg + 4 * H;
            union { u16 u[4]; unsigned long long ll; } pk;
#pragma unroll
            for (int r2 = 0; r2 < 4; ++r2)
                pk.u[r2] = f2b(o[ngd][4 * rg + r2] * linv);
            *reinterpret_cast<unsigned long long*>(aorow + dbase) = pk.ll;
        }
    }
}

// ---------- GEMM2: out = ao @ W_out + b_out, BM=64 BN=128 ----------
// R15: issue-early double-buffered staging with counted vmcnt(6) — tile t+1's
// loads stay in flight across both barriers (T3-minimum recipe).
__global__ __launch_bounds__(256) void gemm_out(const u16* __restrict__ ao,   // [4096][1024]
                                                const u16* __restrict__ wT,   // [1024][1024]
                                                const float* __restrict__ bias,
                                                float* __restrict__ out) {
    __shared__ u16 As[2][64 * 64];
    __shared__ u16 Bs[2][128 * 64];
    const int id = blockIdx.y * 8 + blockIdx.x;
    const int xcd = id & 7, pos = id >> 3;       // 64 blocks per XCD
    const int xr = xcd >> 1, xc = xcd & 1;       // 4 row-groups x 2 col-groups
    const int pr = pos >> 2, pc = pos & 3;       // 16 x 4 rectangle
    const int m0 = (xr * 16 + pr) * 64;          // 64 rows
    const int n0 = (xc * 4 + pc) * 128;          // 8 cols
    const int tid = threadIdx.x;
    const int w = tid >> 6, lane = tid & 63, lr = lane & 15, h = lane >> 4;
    f32x4 acc[4][2] = {};

#define GO_STAGE(buf, kt) do {                                                        \
    _Pragma("unroll")                                                                 \
    for (int j = 0; j < 2; ++j) {                                                     \
        int L = j * 256 + tid;                                                        \
        int r = L >> 3, c = L & 7;                                                    \
        gld16(ao + (size_t)(m0 + r) * 1024 + (kt) * 64 + ((c ^ (r & 7)) << 3),        \
              As[buf] + L * 8);                                                       \
    }                                                                                 \
    _Pragma("unroll")                                                                 \
    for (int j = 0; j < 4; ++j) {                                                     \
        int L = j * 256 + tid;                                                        \
        int r = L >> 3, c = L & 7;                                                    \
        gld16(wT + (size_t)(n0 + r) * 1024 + (kt) * 64 + ((c ^ (r & 7)) << 3),        \
              Bs[buf] + L * 8);                                                       \
    } } while (0)

    GO_STAGE(0, 0);
    int cur = 0;
#pragma unroll 1
    for (int kt = 0; kt < 16; ++kt) {
        if (kt < 15) {
            GO_STAGE(cur ^ 1, kt + 1);
            asm volatile("s_waitcnt vmcnt(6)" ::: "memory");   // tile kt landed; kt+1 in flight
        } else {
            asm volatile("s_waitcnt vmcnt(0)" ::: "memory");
        }
        __builtin_amdgcn_s_barrier();
#pragma unroll
        for (int kk = 0; kk < 2; ++kk) {
            bf16x8 a[4], b[2];
            int cc = kk * 4 + h;
#pragma unroll
            for (int m = 0; m < 4; ++m) {
                int R = m * 16 + lr;
                a[m] = *reinterpret_cast<const bf16x8*>((const char*)As[cur] + R * 128 + ((cc ^ (R & 7)) << 4));
            }
#pragma unroll
            for (int n = 0; n < 2; ++n) {
                int R = w * 32 + n * 16 + lr;
                b[n] = *reinterpret_cast<const bf16x8*>((const char*)Bs[cur] + R * 128 + ((cc ^ (R & 7)) << 4));
            }
            __builtin_amdgcn_s_setprio(1);
#pragma unroll
            for (int m = 0; m < 4; ++m)
#pragma unroll
                for (int n = 0; n < 2; ++n)
                    acc[m][n] = __builtin_amdgcn_mfma_f32_16x16x32_bf16(a[m], b[n], acc[m][n], 0, 0, 0);
            __builtin_amdgcn_s_setprio(0);
        }
        __builtin_amdgcn_sched_barrier(0);
        __builtin_amdgcn_s_barrier();
        cur ^= 1;
    }
#undef GO_STAGE

#pragma unroll
    for (int n = 0; n < 2; ++n) {
        int ng = n0 + w * 32 + n * 16 + lr;
        float bv = bias[ng];
#pragma unroll
        for (int m = 0; m < 4; ++m) {
#pragma unroll
            for (int reg = 0; reg < 4; ++reg) {
                int mg = m0 + m * 16 + h * 4 + reg;
                out[(size_t)mg * 1024 + ng] = acc[m][n][reg] + bv;
            }
        }
    }
}

extern "C" void kernel_launch(void* const* d_in, const int* in_sizes, int n_in,
                              void* d_out, int out_size, void* d_ws, size_t ws_size,
                              hipStream_t stream) {
    const float* x     = (const float*)d_in[0];
    const float* W_qkv = (const float*)d_in[1];
    const float* b_qkv = (const float*)d_in[2];
    const float* W_out = (const float*)d_in[3];
    const float* b_out = (const float*)d_in[4];
    float* out = (float*)d_out;

    char* ws = (char*)d_ws;
    u16* xb    = (u16*)(ws);                       // 8 MB  x bf16 [4096][1024]
    u16* wqkvT = (u16*)(ws + (size_t)( 8u << 20)); // 6 MB  W_qkv^T bf16 [3072][1024]
    u16* woutT = (u16*)(ws + (size_t)(14u << 20)); // 2 MB  W_out^T bf16 [1024][1024]
    u16* qg    = (u16*)(ws + (size_t)(16u << 20)); // 8 MB  Q [B,H,T,D] (pre-scaled)
    u16* kg    = (u16*)(ws + (size_t)(24u << 20)); // 8 MB  K [B,H,T,D]
    u16* vtg   = (u16*)(ws + (size_t)(32u << 20)); // 8 MB  V^T [B,H,D,T] key-permuted
    u16* ao    = xb;                               // reuse x buffer for attn-out

    hipLaunchKernelGGL(prep, dim3(5120), dim3(256), 0, stream, x, xb, W_qkv, wqkvT, W_out, woutT);
    hipLaunchKernelGGL(gemm_qkv, dim3(12, 16), dim3(512), 0, stream, xb, wqkvT, b_qkv, qg, kg, vtg);
    hipLaunchKernelGGL(attn, dim3(32, 16), dim3(256), 0, stream, qg, kg, vtg, ao);
    hipLaunchKernelGGL(gemm_out, dim3(8, 64), dim3(256), 0, stream, ao, woutT, b_out, out);
}